// Round 3
// baseline (566.248 us; speedup 1.0000x reference)
//
#include <hip/hip_runtime.h>
#include <hip/hip_bf16.h>

typedef unsigned short u16;
typedef __bf16 bf16x8 __attribute__((ext_vector_type(8)));
typedef float f32x4 __attribute__((ext_vector_type(4)));
typedef float f32x16 __attribute__((ext_vector_type(16)));

#define NN 20000
#define NE 320000

// ---------------- ws layout (bytes) ----------------
// 32x32-swizzled weights (edge pipeline)
constexpr size_t SZ_W1  = (size_t)18 * 17 * 512 * 2;  // eW1: K 288, N 544
constexpr size_t SZ_W2  = (size_t)34 * 4  * 512 * 2;  // eW2: K 544, N 128
constexpr size_t SZ_WC1 = (size_t)8  * 8  * 512 * 2;  // cW1: K 128, N 256
constexpr size_t SZ_WC2 = (size_t)16 * 1  * 512 * 2;  // cW2: K 256, N 32(3)
// 16x16-swizzled weights (node kernel, unchanged)
constexpr size_t SZ_WN1 = (size_t)8  * 32 * 512 * 2;  // nW1: K 256, N 512
constexpr size_t SZ_WN2 = (size_t)16 * 8  * 512 * 2;  // nW2: K 512, N 128
constexpr size_t OFF_W1   = 0;
constexpr size_t OFF_W2   = OFF_W1 + SZ_W1;
constexpr size_t OFF_WC1  = OFF_W2 + SZ_W2;
constexpr size_t OFF_WC2  = OFF_WC1 + SZ_WC1;
constexpr size_t OFF_WN1  = OFF_WC2 + SZ_WC2;
constexpr size_t OFF_WN2  = OFF_WN1 + SZ_WN1;
constexpr size_t OFF_HB   = OFF_WN2 + SZ_WN2;         // h as bf16 [NN,128]
constexpr size_t SZ_HB    = (size_t)NN * 128 * 2;
constexpr size_t OFF_AGGH = OFF_HB + SZ_HB;           // f32 [NN,128]
constexpr size_t SZ_AGGH  = (size_t)NN * 128 * 4;
constexpr size_t OFF_AGGC = OFF_AGGH + SZ_AGGH;       // f32 [NN,9]
constexpr size_t SZ_AGGC  = (size_t)NN * 9 * 4;
constexpr size_t OFF_CNT  = OFF_AGGC + SZ_AGGC;       // f32 [NN]
constexpr size_t SZ_CNT   = (size_t)NN * 4;

__device__ __forceinline__ u16 f2b(float x) {
  union { float f; unsigned u; } v; v.f = x;
  unsigned r = (v.u + 0x7fffu + ((v.u >> 16) & 1u)) >> 16;
  return (u16)r;
}
__device__ __forceinline__ float silu_f(float x) {
  float e = __builtin_amdgcn_exp2f(-1.44269504088896f * x);
  return x * __builtin_amdgcn_rcpf(1.f + e);
}

// 16x16 B-fragment swizzle (node kernel weights)
__global__ void swz_kernel(const float* __restrict__ W, u16* __restrict__ dst,
                           int Kreal, int Nreal, int KT, int NT) {
  int idx = blockIdx.x * 256 + threadIdx.x;
  int total = KT * NT * 512;
  if (idx >= total) return;
  int e = idx & 7, l = (idx >> 3) & 63, blk = idx >> 9;
  int kt = blk % KT, nt = blk / KT;
  int k = kt * 32 + ((l >> 4) * 8) + e;
  int n = nt * 16 + (l & 15);
  float v = (k < Kreal && n < Nreal) ? W[(size_t)k * Nreal + n] : 0.f;
  dst[idx] = f2b(v);
}

// 32x32 B-fragment swizzle: dst[((nt*KT+kt)*64+l)*8+e] = W[kt*16+(l>>5)*8+e][nt*32+(l&31)]
__global__ void swz32_kernel(const float* __restrict__ W, u16* __restrict__ dst,
                             int Kreal, int Nreal, int KT, int NT) {
  int idx = blockIdx.x * 256 + threadIdx.x;
  int total = KT * NT * 512;
  if (idx >= total) return;
  int e = idx & 7, l = (idx >> 3) & 63, blk = idx >> 9;
  int kt = blk % KT, nt = blk / KT;
  int k = kt * 16 + ((l >> 5) * 8) + e;
  int n = nt * 32 + (l & 31);
  float v = (k < Kreal && n < Nreal) ? W[(size_t)k * Nreal + n] : 0.f;
  dst[idx] = f2b(v);
}

__global__ void tob16_kernel(const float* __restrict__ x, u16* __restrict__ y, int n) {
  int i = blockIdx.x * 256 + threadIdx.x;
  if (i < n) y[i] = f2b(x[i]);
}

// ---------------- fused edge pipeline: M=128, 8 waves, 32x32x16 MFMA ----------------
// wave w: mh = w&1 (m-tiles 2mh,2mh+1 -> rows mh*64 + {0..63}), nh = w>>1 (0..3)
__global__ __launch_bounds__(512)
void edge_kernel(const u16* __restrict__ hb, const int* __restrict__ eidx,
                 const float* __restrict__ coord,
                 const u16* __restrict__ W1s, const float* __restrict__ b1,
                 const u16* __restrict__ W2s, const float* __restrict__ b2,
                 const u16* __restrict__ WC1s, const float* __restrict__ bc1,
                 const u16* __restrict__ WC2s,
                 float* __restrict__ agg_h, float* __restrict__ agg_c,
                 float* __restrict__ cnt) {
  __shared__ __align__(16) u16 bufA[128 * 296];  // A1 [128][288+8] -> Y3 [128][264]
  __shared__ __align__(16) u16 bufB[128 * 264];  // Y1 chunk [128][256+8] -> ef [128][136]
  __shared__ float cd_s[128][9];
  __shared__ float phi_s[128][4];
  __shared__ int row_s[128];
  __shared__ int col_s[128];

  const int tid = threadIdx.x;
  const int lane = tid & 63;
  const int w = tid >> 6;
  const int l5 = lane & 31;
  const int hi = lane >> 5;
  const int mh = w & 1;
  const int nh = w >> 1;
  const int e0 = blockIdx.x << 7;

  if (tid < 128) row_s[tid] = eidx[e0 + tid];
  else if (tid < 256) col_s[tid - 128] = eidx[NE + e0 + tid - 128];
  __syncthreads();

  // radial (2 waves) + h gather (all)
  if (tid < 128) {
    const int r = row_s[tid], c = col_s[tid];
    float cd[9];
    #pragma unroll
    for (int i = 0; i < 9; i++) { cd[i] = coord[r * 9 + i] - coord[c * 9 + i]; cd_s[tid][i] = cd[i]; }
    u16* arow = bufA + tid * 296;
    #pragma unroll
    for (int a = 0; a < 3; a++)
      #pragma unroll
      for (int b = 0; b < 3; b++) {
        float rad = cd[a*3]*cd[b*3] + cd[a*3+1]*cd[b*3+1] + cd[a*3+2]*cd[b*3+2];
        arow[256 + a * 3 + b] = f2b(rad);
      }
    #pragma unroll
    for (int k = 265; k < 288; k++) arow[k] = (u16)0;
  }
  for (int q = tid; q < 4096; q += 512) {
    const int e = q >> 5, sub = q & 31, which = sub >> 4, j = sub & 15;
    const int node = which ? col_s[e] : row_s[e];
    const int4 v = *reinterpret_cast<const int4*>(hb + (size_t)node * 128 + j * 8);
    *reinterpret_cast<int4*>(bufA + e * 296 + which * 128 + j * 8) = v;
  }
  __syncthreads();

  // ---- chunked GEMM1 [128,288]x[288,544] -> silu -> GEMM2 [128,544]x[544,128] ----
  // chunk c: GEMM1 n-tiles(32) c*8 + nh*2 + {0,1} (valid < 17), bufB cols = chunk-local
  f32x16 acc2[2];
  #pragma unroll
  for (int j = 0; j < 2; j++)
    #pragma unroll
    for (int t = 0; t < 16; t++) acc2[j][t] = 0.f;

  for (int c = 0; c < 3; c++) {
    const int ntA = c * 8 + nh * 2;
    const int ntB = ntA + 1;
    f32x16 acc1[2][2];
    #pragma unroll
    for (int i = 0; i < 2; i++)
      #pragma unroll
      for (int j = 0; j < 2; j++)
        #pragma unroll
        for (int t = 0; t < 16; t++) acc1[i][j][t] = 0.f;

    for (int kt = 0; kt < 18; kt++) {
      const bf16x8 af0 = *reinterpret_cast<const bf16x8*>(bufA + (mh * 64 + l5) * 296 + kt * 16 + hi * 8);
      const bf16x8 af1 = *reinterpret_cast<const bf16x8*>(bufA + (mh * 64 + 32 + l5) * 296 + kt * 16 + hi * 8);
      if (ntA < 17) {
        const bf16x8 b0 = *reinterpret_cast<const bf16x8*>(W1s + (((ntA * 18 + kt) << 6) + lane) * 8);
        acc1[0][0] = __builtin_amdgcn_mfma_f32_32x32x16_bf16(af0, b0, acc1[0][0], 0, 0, 0);
        acc1[0][1] = __builtin_amdgcn_mfma_f32_32x32x16_bf16(af1, b0, acc1[0][1], 0, 0, 0);
      }
      if (ntB < 17) {
        const bf16x8 b1f = *reinterpret_cast<const bf16x8*>(W1s + (((ntB * 18 + kt) << 6) + lane) * 8);
        acc1[1][0] = __builtin_amdgcn_mfma_f32_32x32x16_bf16(af0, b1f, acc1[1][0], 0, 0, 0);
        acc1[1][1] = __builtin_amdgcn_mfma_f32_32x32x16_bf16(af1, b1f, acc1[1][1], 0, 0, 0);
      }
    }
    __syncthreads();  // prev chunk's GEMM2 reads of bufB complete
    #pragma unroll
    for (int i = 0; i < 2; i++) {
      const int nt = c * 8 + nh * 2 + i;
      if (nt < 17) {
        const int colg = nt * 32 + l5;
        const float bias = (colg < 530) ? b1[colg] : 0.f;
        const int coll = (nh * 2 + i) * 32 + l5;
        #pragma unroll
        for (int j = 0; j < 2; j++)
          #pragma unroll
          for (int r = 0; r < 16; r++) {
            const int rowi = mh * 64 + j * 32 + ((r & 3) + 8 * (r >> 2) + 4 * hi);
            bufB[rowi * 264 + coll] = f2b(silu_f(acc1[i][j][r] + bias));
          }
      }
    }
    __syncthreads();  // Y1 chunk ready
    const int nk2 = (c < 2) ? 16 : 2;
    for (int k2 = 0; k2 < nk2; k2++) {
      const bf16x8 a0 = *reinterpret_cast<const bf16x8*>(bufB + (mh * 64 + l5) * 264 + k2 * 16 + hi * 8);
      const bf16x8 a1 = *reinterpret_cast<const bf16x8*>(bufB + (mh * 64 + 32 + l5) * 264 + k2 * 16 + hi * 8);
      const bf16x8 bw = *reinterpret_cast<const bf16x8*>(W2s + (((nh * 34 + c * 16 + k2) << 6) + lane) * 8);
      acc2[0] = __builtin_amdgcn_mfma_f32_32x32x16_bf16(a0, bw, acc2[0], 0, 0, 0);
      acc2[1] = __builtin_amdgcn_mfma_f32_32x32x16_bf16(a1, bw, acc2[1], 0, 0, 0);
    }
  }
  __syncthreads();  // all GEMM2 reads done

  // ef = silu(acc2 + b2) -> bufB as [128][136] + atomic agg_h
  {
    const int col = nh * 32 + l5;
    const float bias = b2[col];
    #pragma unroll
    for (int j = 0; j < 2; j++)
      #pragma unroll
      for (int r = 0; r < 16; r++) {
        const int rowi = mh * 64 + j * 32 + ((r & 3) + 8 * (r >> 2) + 4 * hi);
        const float ef = silu_f(acc2[j][r] + bias);
        bufB[rowi * 136 + col] = f2b(ef);
        atomicAdd(&agg_h[(size_t)row_s[rowi] * 128 + col], ef);
      }
  }
  __syncthreads();

  // GEMM3: ef[128,128] x WC1[128,256]; wave: n-tiles nh*2+{0,1}, m-tiles 2mh+{0,1}
  f32x16 acc3[2][2];
  #pragma unroll
  for (int i = 0; i < 2; i++)
    #pragma unroll
    for (int j = 0; j < 2; j++)
      #pragma unroll
      for (int t = 0; t < 16; t++) acc3[i][j][t] = 0.f;
  for (int kt = 0; kt < 8; kt++) {
    const bf16x8 a0 = *reinterpret_cast<const bf16x8*>(bufB + (mh * 64 + l5) * 136 + kt * 16 + hi * 8);
    const bf16x8 a1 = *reinterpret_cast<const bf16x8*>(bufB + (mh * 64 + 32 + l5) * 136 + kt * 16 + hi * 8);
    #pragma unroll
    for (int i = 0; i < 2; i++) {
      const int nt = nh * 2 + i;
      const bf16x8 bw = *reinterpret_cast<const bf16x8*>(WC1s + (((nt * 8 + kt) << 6) + lane) * 8);
      acc3[i][0] = __builtin_amdgcn_mfma_f32_32x32x16_bf16(a0, bw, acc3[i][0], 0, 0, 0);
      acc3[i][1] = __builtin_amdgcn_mfma_f32_32x32x16_bf16(a1, bw, acc3[i][1], 0, 0, 0);
    }
  }
  // epi3 -> bufA as Y3 [128][264] (bufA's A1 fully consumed before the post-loop barrier)
  #pragma unroll
  for (int i = 0; i < 2; i++) {
    const int col = (nh * 2 + i) * 32 + l5;
    const float bias = bc1[col];
    #pragma unroll
    for (int j = 0; j < 2; j++)
      #pragma unroll
      for (int r = 0; r < 16; r++) {
        const int rowi = mh * 64 + j * 32 + ((r & 3) + 8 * (r >> 2) + 4 * hi);
        bufA[rowi * 264 + col] = f2b(silu_f(acc3[i][j][r] + bias));
      }
  }
  __syncthreads();

  // GEMM4: Y3[128,256] x WC2[256,32(3)]; waves 0..3: m-tile w
  if (w < 4) {
    f32x16 acc4;
    #pragma unroll
    for (int t = 0; t < 16; t++) acc4[t] = 0.f;
    for (int kt = 0; kt < 16; kt++) {
      const bf16x8 a = *reinterpret_cast<const bf16x8*>(bufA + (w * 32 + l5) * 264 + kt * 16 + hi * 8);
      const bf16x8 bw = *reinterpret_cast<const bf16x8*>(WC2s + ((kt << 6) + lane) * 8);
      acc4 = __builtin_amdgcn_mfma_f32_32x32x16_bf16(a, bw, acc4, 0, 0, 0);
    }
    if (l5 < 3) {
      #pragma unroll
      for (int r = 0; r < 16; r++)
        phi_s[w * 32 + ((r & 3) + 8 * (r >> 2) + 4 * hi)][l5] = acc4[r];
    }
  }
  __syncthreads();

  if (tid < 128) {
    const int node = row_s[tid];
    const float p0 = phi_s[tid][0], p1 = phi_s[tid][1], p2 = phi_s[tid][2];
    #pragma unroll
    for (int d = 0; d < 3; d++) {
      atomicAdd(&agg_c[(size_t)node * 9 + 0 + d], cd_s[tid][0 + d] * p0);
      atomicAdd(&agg_c[(size_t)node * 9 + 3 + d], cd_s[tid][3 + d] * p1);
      atomicAdd(&agg_c[(size_t)node * 9 + 6 + d], cd_s[tid][6 + d] * p2);
    }
    atomicAdd(&cnt[node], 1.f);
  }
}

// ---------------- node MLP (unchanged 16x16 path) ----------------
__global__ __launch_bounds__(512)
void node_kernel(const float* __restrict__ h, const u16* __restrict__ hb,
                 const float* __restrict__ agg_h,
                 const u16* __restrict__ WN1s, const float* __restrict__ nb1,
                 const u16* __restrict__ WN2s, const float* __restrict__ nb2,
                 float* __restrict__ out) {
  __shared__ __align__(16) u16 buf[64 * 520];
  const int tid = threadIdx.x;
  const int lane = tid & 63;
  const int w = tid >> 6;
  const int l_lo = lane & 15;
  const int l_hi = lane >> 4;
  const int n0 = blockIdx.x << 6;

  for (int q = tid; q < 1024; q += 512) {
    const int e = q >> 4, j = q & 15;
    const int row = n0 + e;
    int4 v;
    if (row < NN) v = *reinterpret_cast<const int4*>(hb + (size_t)row * 128 + j * 8);
    else { v.x = v.y = v.z = v.w = 0; }
    *reinterpret_cast<int4*>(buf + e * 264 + j * 8) = v;
  }
  for (int q = tid; q < 8192; q += 512) {
    const int e = q >> 7, k = q & 127;
    const int row = n0 + e;
    const float v = (row < NN) ? agg_h[(size_t)row * 128 + k] : 0.f;
    buf[e * 264 + 128 + k] = f2b(v);
  }
  __syncthreads();

  f32x4 acc[4][4];
  #pragma unroll
  for (int i = 0; i < 4; i++)
    #pragma unroll
    for (int m = 0; m < 4; m++) acc[i][m] = {0.f, 0.f, 0.f, 0.f};
  for (int kt = 0; kt < 8; kt++) {
    bf16x8 af[4];
    #pragma unroll
    for (int m = 0; m < 4; m++)
      af[m] = *reinterpret_cast<const bf16x8*>(buf + (m * 16 + l_lo) * 264 + kt * 32 + l_hi * 8);
    #pragma unroll
    for (int i = 0; i < 4; i++) {
      const int nt = w + 8 * i;
      const bf16x8 bfr = *reinterpret_cast<const bf16x8*>(WN1s + (((nt * 8 + kt) << 6) + lane) * 8);
      #pragma unroll
      for (int m = 0; m < 4; m++)
        acc[i][m] = __builtin_amdgcn_mfma_f32_16x16x32_bf16(af[m], bfr, acc[i][m], 0, 0, 0);
    }
  }
  __syncthreads();
  #pragma unroll
  for (int i = 0; i < 4; i++) {
    const int nt = w + 8 * i;
    const int coln = nt * 16 + l_lo;
    const float bias = nb1[coln];
    #pragma unroll
    for (int m = 0; m < 4; m++)
      #pragma unroll
      for (int r = 0; r < 4; r++) {
        const int row = m * 16 + l_hi * 4 + r;
        buf[row * 520 + coln] = f2b(silu_f(acc[i][m][r] + bias));
      }
  }
  __syncthreads();

  f32x4 acc2[4];
  #pragma unroll
  for (int m = 0; m < 4; m++) acc2[m] = {0.f, 0.f, 0.f, 0.f};
  for (int kt = 0; kt < 16; kt++) {
    const bf16x8 bfr = *reinterpret_cast<const bf16x8*>(WN2s + (((w * 16 + kt) << 6) + lane) * 8);
    #pragma unroll
    for (int m = 0; m < 4; m++) {
      const bf16x8 af = *reinterpret_cast<const bf16x8*>(buf + (m * 16 + l_lo) * 520 + kt * 32 + l_hi * 8);
      acc2[m] = __builtin_amdgcn_mfma_f32_16x16x32_bf16(af, bfr, acc2[m], 0, 0, 0);
    }
  }
  {
    const int coln = w * 16 + l_lo;
    const float bias = nb2[coln];
    #pragma unroll
    for (int m = 0; m < 4; m++)
      #pragma unroll
      for (int r = 0; r < 4; r++) {
        const int row = n0 + m * 16 + l_hi * 4 + r;
        if (row < NN)
          out[(size_t)row * 128 + coln] = h[(size_t)row * 128 + coln] + silu_f(acc2[m][r] + bias);
      }
  }
}

__global__ void coord_kernel(const float* __restrict__ coord, const float* __restrict__ agg_c,
                             const float* __restrict__ cnt, float* __restrict__ out) {
  int i = blockIdx.x * 256 + threadIdx.x;
  if (i < NN * 9) {
    float c = fmaxf(cnt[i / 9], 1.f);
    float v = agg_c[i] / c;
    v = fminf(fmaxf(v, -10.f), 10.f);
    out[i] = coord[i] + v;
  }
}

extern "C" void kernel_launch(void* const* d_in, const int* in_sizes, int n_in,
                              void* d_out, int out_size, void* d_ws, size_t ws_size,
                              hipStream_t stream) {
  (void)in_sizes; (void)n_in; (void)out_size; (void)ws_size;
  const float* h     = (const float*)d_in[0];
  const int*   eidx  = (const int*)d_in[1];
  const float* coord = (const float*)d_in[2];
  const float* eW1 = (const float*)d_in[3];  const float* eb1 = (const float*)d_in[4];
  const float* eW2 = (const float*)d_in[5];  const float* eb2 = (const float*)d_in[6];
  const float* nW1 = (const float*)d_in[7];  const float* nb1 = (const float*)d_in[8];
  const float* nW2 = (const float*)d_in[9];  const float* nb2 = (const float*)d_in[10];
  const float* cW1 = (const float*)d_in[11]; const float* cb1 = (const float*)d_in[12];
  const float* cW2 = (const float*)d_in[13];

  char* ws = (char*)d_ws;
  u16* W1s  = (u16*)(ws + OFF_W1);
  u16* W2s  = (u16*)(ws + OFF_W2);
  u16* WC1s = (u16*)(ws + OFF_WC1);
  u16* WC2s = (u16*)(ws + OFF_WC2);
  u16* WN1s = (u16*)(ws + OFF_WN1);
  u16* WN2s = (u16*)(ws + OFF_WN2);
  u16* hb   = (u16*)(ws + OFF_HB);
  float* agg_h = (float*)(ws + OFF_AGGH);
  float* agg_c = (float*)(ws + OFF_AGGC);
  float* cnt   = (float*)(ws + OFF_CNT);
  float* out   = (float*)d_out;

  hipMemsetAsync(ws + OFF_AGGH, 0, SZ_AGGH + SZ_AGGC + SZ_CNT, stream);

  swz32_kernel<<<18 * 17 * 2, 256, 0, stream>>>(eW1, W1s, 265, 530, 18, 17);
  swz32_kernel<<<34 * 4 * 2, 256, 0, stream>>>(eW2, W2s, 530, 128, 34, 4);
  swz32_kernel<<<8 * 8 * 2, 256, 0, stream>>>(cW1, WC1s, 128, 256, 8, 8);
  swz32_kernel<<<16 * 1 * 2, 256, 0, stream>>>(cW2, WC2s, 256, 3, 16, 1);
  swz_kernel<<<8 * 32 * 2, 256, 0, stream>>>(nW1, WN1s, 256, 512, 8, 32);
  swz_kernel<<<16 * 8 * 2, 256, 0, stream>>>(nW2, WN2s, 512, 128, 16, 8);
  tob16_kernel<<<(NN * 128 + 255) / 256, 256, 0, stream>>>(h, hb, NN * 128);

  edge_kernel<<<NE / 128, 512, 0, stream>>>(hb, eidx, coord, W1s, eb1, W2s, eb2,
                                            WC1s, cb1, WC2s, agg_h, agg_c, cnt);
  node_kernel<<<(NN + 63) / 64, 512, 0, stream>>>(h, hb, agg_h, WN1s, nb1, WN2s, nb2, out);
  coord_kernel<<<(NN * 9 + 255) / 256, 256, 0, stream>>>(coord, agg_c, cnt, out + (size_t)NN * 128);
}

// Round 4
// 447.401 us; speedup vs baseline: 1.2656x; 1.2656x over previous
//
#include <hip/hip_runtime.h>
#include <hip/hip_bf16.h>

typedef unsigned short u16;
typedef __bf16 bf16x8 __attribute__((ext_vector_type(8)));
typedef float f32x4 __attribute__((ext_vector_type(4)));
typedef float f32x16 __attribute__((ext_vector_type(16)));

#define NN 20000
#define NE 320000

// ---------------- ws layout (bytes) ----------------
// 32x32-swizzled weights (edge pipeline)
constexpr size_t SZ_W1  = (size_t)18 * 17 * 512 * 2;  // eW1: K 288, N 544
constexpr size_t SZ_W2  = (size_t)34 * 4  * 512 * 2;  // eW2: K 544, N 128
constexpr size_t SZ_WC1 = (size_t)8  * 8  * 512 * 2;  // cW1: K 128, N 256
constexpr size_t SZ_WC2 = (size_t)16 * 1  * 512 * 2;  // cW2: K 256, N 32(3)
// 16x16-swizzled weights (node kernel)
constexpr size_t SZ_WN1 = (size_t)8  * 32 * 512 * 2;  // nW1: K 256, N 512
constexpr size_t SZ_WN2 = (size_t)16 * 8  * 512 * 2;  // nW2: K 512, N 128
constexpr size_t OFF_W1   = 0;
constexpr size_t OFF_W2   = OFF_W1 + SZ_W1;
constexpr size_t OFF_WC1  = OFF_W2 + SZ_W2;
constexpr size_t OFF_WC2  = OFF_WC1 + SZ_WC1;
constexpr size_t OFF_WN1  = OFF_WC2 + SZ_WC2;
constexpr size_t OFF_WN2  = OFF_WN1 + SZ_WN1;
constexpr size_t OFF_HB   = OFF_WN2 + SZ_WN2;         // h as bf16 [NN,128]
constexpr size_t SZ_HB    = (size_t)NN * 128 * 2;
constexpr size_t OFF_AGGH = OFF_HB + SZ_HB;           // f32 [NN,128]
constexpr size_t SZ_AGGH  = (size_t)NN * 128 * 4;
constexpr size_t OFF_AGGC = OFF_AGGH + SZ_AGGH;       // f32 [NN,9]
constexpr size_t SZ_AGGC  = (size_t)NN * 9 * 4;
constexpr size_t OFF_CNT  = OFF_AGGC + SZ_AGGC;       // f32 [NN]
constexpr size_t SZ_CNT   = (size_t)NN * 4;

__device__ __forceinline__ u16 f2b(float x) {
  union { float f; unsigned u; } v; v.f = x;
  unsigned r = (v.u + 0x7fffu + ((v.u >> 16) & 1u)) >> 16;
  return (u16)r;
}
__device__ __forceinline__ float silu_f(float x) {
  float e = __builtin_amdgcn_exp2f(-1.44269504088896f * x);
  return x * __builtin_amdgcn_rcpf(1.f + e);
}

// 16x16 B-fragment swizzle (node kernel weights)
__global__ void swz_kernel(const float* __restrict__ W, u16* __restrict__ dst,
                           int Kreal, int Nreal, int KT, int NT) {
  int idx = blockIdx.x * 256 + threadIdx.x;
  int total = KT * NT * 512;
  if (idx >= total) return;
  int e = idx & 7, l = (idx >> 3) & 63, blk = idx >> 9;
  int kt = blk % KT, nt = blk / KT;
  int k = kt * 32 + ((l >> 4) * 8) + e;
  int n = nt * 16 + (l & 15);
  float v = (k < Kreal && n < Nreal) ? W[(size_t)k * Nreal + n] : 0.f;
  dst[idx] = f2b(v);
}

// 32x32 B-fragment swizzle: dst[((nt*KT+kt)*64+l)*8+e] = W[kt*16+(l>>5)*8+e][nt*32+(l&31)]
__global__ void swz32_kernel(const float* __restrict__ W, u16* __restrict__ dst,
                             int Kreal, int Nreal, int KT, int NT) {
  int idx = blockIdx.x * 256 + threadIdx.x;
  int total = KT * NT * 512;
  if (idx >= total) return;
  int e = idx & 7, l = (idx >> 3) & 63, blk = idx >> 9;
  int kt = blk % KT, nt = blk / KT;
  int k = kt * 16 + ((l >> 5) * 8) + e;
  int n = nt * 32 + (l & 31);
  float v = (k < Kreal && n < Nreal) ? W[(size_t)k * Nreal + n] : 0.f;
  dst[idx] = f2b(v);
}

__global__ void tob16_kernel(const float* __restrict__ x, u16* __restrict__ y, int n) {
  int i = blockIdx.x * 256 + threadIdx.x;
  if (i < n) y[i] = f2b(x[i]);
}

// ---------------- fused edge pipeline: M=64, 8 waves, 32x32x16, 2 blocks/CU ----------------
// wave w: mh = w&1 (m-tile, rows mh*32+l5), nh = w>>1 (n-group 0..3)
__global__ __launch_bounds__(512, 4)
void edge_kernel(const u16* __restrict__ hb, const int* __restrict__ eidx,
                 const float* __restrict__ coord,
                 const u16* __restrict__ W1s, const float* __restrict__ b1,
                 const u16* __restrict__ W2s, const float* __restrict__ b2,
                 const u16* __restrict__ WC1s, const float* __restrict__ bc1,
                 const u16* __restrict__ WC2s,
                 float* __restrict__ agg_h, float* __restrict__ agg_c,
                 float* __restrict__ cnt) {
  __shared__ __align__(16) u16 bufA[64 * 296];  // A1 [64][288+8] -> Y3 [64][264]
  __shared__ __align__(16) u16 bufB[64 * 136];  // Y1 chunk [64][128+8] -> ef [64][136]
  __shared__ float cd_s[64][9];
  __shared__ float phi_s[64][4];
  __shared__ int row_s[64];
  __shared__ int col_s[64];

  const int tid = threadIdx.x;
  const int lane = tid & 63;
  const int w = tid >> 6;
  const int l5 = lane & 31;
  const int hi = lane >> 5;
  const int mh = w & 1;
  const int nh = w >> 1;
  const int e0 = blockIdx.x << 6;

  if (tid < 64) row_s[tid] = eidx[e0 + tid];
  else if (tid < 128) col_s[tid - 64] = eidx[NE + e0 + tid - 64];
  __syncthreads();

  // radial (wave 0) + h gather (all waves) -> bufA
  if (tid < 64) {
    const int r = row_s[tid], c = col_s[tid];
    float cd[9];
    #pragma unroll
    for (int i = 0; i < 9; i++) { cd[i] = coord[r * 9 + i] - coord[c * 9 + i]; cd_s[tid][i] = cd[i]; }
    u16* arow = bufA + tid * 296;
    #pragma unroll
    for (int a = 0; a < 3; a++)
      #pragma unroll
      for (int b = 0; b < 3; b++) {
        float rad = cd[a*3]*cd[b*3] + cd[a*3+1]*cd[b*3+1] + cd[a*3+2]*cd[b*3+2];
        arow[256 + a * 3 + b] = f2b(rad);
      }
    #pragma unroll
    for (int k = 265; k < 288; k++) arow[k] = (u16)0;
  }
  for (int q = tid; q < 2048; q += 512) {
    const int e = q >> 5, sub = q & 31, which = sub >> 4, j = sub & 15;
    const int node = which ? col_s[e] : row_s[e];
    const int4 v = *reinterpret_cast<const int4*>(hb + (size_t)node * 128 + j * 8);
    *reinterpret_cast<int4*>(bufA + e * 296 + which * 128 + j * 8) = v;
  }
  __syncthreads();

  // ---- chunked GEMM1 [64,288]x[288,544] -> silu -> GEMM2 [64,544]x[544,128] ----
  // chunk c (0..4): GEMM1 n-tile nt = c*4 + nh (valid < 17); bufB cols chunk-local (128)
  f32x16 acc2;
  #pragma unroll
  for (int t = 0; t < 16; t++) acc2[t] = 0.f;

  for (int c = 0; c < 5; c++) {
    const int nt = c * 4 + nh;
    f32x16 acc1;
    #pragma unroll
    for (int t = 0; t < 16; t++) acc1[t] = 0.f;

    if (nt < 17) {
      for (int kt = 0; kt < 18; kt++) {
        const bf16x8 af = *reinterpret_cast<const bf16x8*>(bufA + (mh * 32 + l5) * 296 + kt * 16 + hi * 8);
        const bf16x8 bw = *reinterpret_cast<const bf16x8*>(W1s + (((nt * 18 + kt) << 6) + lane) * 8);
        acc1 = __builtin_amdgcn_mfma_f32_32x32x16_bf16(af, bw, acc1, 0, 0, 0);
      }
    }
    __syncthreads();  // prev chunk's GEMM2 reads of bufB complete
    if (nt < 17) {
      const int colg = nt * 32 + l5;
      const float bias = (colg < 530) ? b1[colg] : 0.f;
      const int coll = nh * 32 + l5;
      #pragma unroll
      for (int r = 0; r < 16; r++) {
        const int rowi = mh * 32 + ((r & 3) + 8 * (r >> 2) + 4 * hi);
        bufB[rowi * 136 + coll] = f2b(silu_f(acc1[r] + bias));
      }
    }
    __syncthreads();  // Y1 chunk ready
    const int nk2 = (c < 4) ? 8 : 2;
    for (int k2 = 0; k2 < nk2; k2++) {
      const bf16x8 a = *reinterpret_cast<const bf16x8*>(bufB + (mh * 32 + l5) * 136 + k2 * 16 + hi * 8);
      const bf16x8 bw = *reinterpret_cast<const bf16x8*>(W2s + (((nh * 34 + c * 8 + k2) << 6) + lane) * 8);
      acc2 = __builtin_amdgcn_mfma_f32_32x32x16_bf16(a, bw, acc2, 0, 0, 0);
    }
  }
  __syncthreads();  // all GEMM2 reads of bufB done

  // ef = silu(acc2 + b2) -> bufB [64][136] + atomic agg_h
  {
    const int col = nh * 32 + l5;
    const float bias = b2[col];
    #pragma unroll
    for (int r = 0; r < 16; r++) {
      const int rowi = mh * 32 + ((r & 3) + 8 * (r >> 2) + 4 * hi);
      const float ef = silu_f(acc2[r] + bias);
      bufB[rowi * 136 + col] = f2b(ef);
      atomicAdd(&agg_h[(size_t)row_s[rowi] * 128 + col], ef);
    }
  }
  __syncthreads();

  // GEMM3: ef[64,128] x WC1[128,256]; wave: m-tile mh, n-tiles nh*2+{0,1}
  f32x16 acc3[2];
  #pragma unroll
  for (int i = 0; i < 2; i++)
    #pragma unroll
    for (int t = 0; t < 16; t++) acc3[i][t] = 0.f;
  for (int kt = 0; kt < 8; kt++) {
    const bf16x8 a = *reinterpret_cast<const bf16x8*>(bufB + (mh * 32 + l5) * 136 + kt * 16 + hi * 8);
    #pragma unroll
    for (int i = 0; i < 2; i++) {
      const int nt = nh * 2 + i;
      const bf16x8 bw = *reinterpret_cast<const bf16x8*>(WC1s + (((nt * 8 + kt) << 6) + lane) * 8);
      acc3[i] = __builtin_amdgcn_mfma_f32_32x32x16_bf16(a, bw, acc3[i], 0, 0, 0);
    }
  }
  // epi3 -> bufA as Y3 [64][264] (A1 fully consumed already)
  #pragma unroll
  for (int i = 0; i < 2; i++) {
    const int col = (nh * 2 + i) * 32 + l5;
    const float bias = bc1[col];
    #pragma unroll
    for (int r = 0; r < 16; r++) {
      const int rowi = mh * 32 + ((r & 3) + 8 * (r >> 2) + 4 * hi);
      bufA[rowi * 264 + col] = f2b(silu_f(acc3[i][r] + bias));
    }
  }
  __syncthreads();

  // GEMM4: Y3[64,256] x WC2[256,32(3)]; waves with nh==0 (w=0,1): m-tile mh
  if (nh == 0) {
    f32x16 acc4;
    #pragma unroll
    for (int t = 0; t < 16; t++) acc4[t] = 0.f;
    for (int kt = 0; kt < 16; kt++) {
      const bf16x8 a = *reinterpret_cast<const bf16x8*>(bufA + (mh * 32 + l5) * 264 + kt * 16 + hi * 8);
      const bf16x8 bw = *reinterpret_cast<const bf16x8*>(WC2s + ((kt << 6) + lane) * 8);
      acc4 = __builtin_amdgcn_mfma_f32_32x32x16_bf16(a, bw, acc4, 0, 0, 0);
    }
    if (l5 < 3) {
      #pragma unroll
      for (int r = 0; r < 16; r++)
        phi_s[mh * 32 + ((r & 3) + 8 * (r >> 2) + 4 * hi)][l5] = acc4[r];
    }
  }
  __syncthreads();

  if (tid < 64) {
    const int node = row_s[tid];
    const float p0 = phi_s[tid][0], p1 = phi_s[tid][1], p2 = phi_s[tid][2];
    #pragma unroll
    for (int d = 0; d < 3; d++) {
      atomicAdd(&agg_c[(size_t)node * 9 + 0 + d], cd_s[tid][0 + d] * p0);
      atomicAdd(&agg_c[(size_t)node * 9 + 3 + d], cd_s[tid][3 + d] * p1);
      atomicAdd(&agg_c[(size_t)node * 9 + 6 + d], cd_s[tid][6 + d] * p2);
    }
    atomicAdd(&cnt[node], 1.f);
  }
}

// ---------------- node MLP (16x16 path) ----------------
__global__ __launch_bounds__(512)
void node_kernel(const float* __restrict__ h, const u16* __restrict__ hb,
                 const float* __restrict__ agg_h,
                 const u16* __restrict__ WN1s, const float* __restrict__ nb1,
                 const u16* __restrict__ WN2s, const float* __restrict__ nb2,
                 float* __restrict__ out) {
  __shared__ __align__(16) u16 buf[64 * 520];
  const int tid = threadIdx.x;
  const int lane = tid & 63;
  const int w = tid >> 6;
  const int l_lo = lane & 15;
  const int l_hi = lane >> 4;
  const int n0 = blockIdx.x << 6;

  for (int q = tid; q < 1024; q += 512) {
    const int e = q >> 4, j = q & 15;
    const int row = n0 + e;
    int4 v;
    if (row < NN) v = *reinterpret_cast<const int4*>(hb + (size_t)row * 128 + j * 8);
    else { v.x = v.y = v.z = v.w = 0; }
    *reinterpret_cast<int4*>(buf + e * 264 + j * 8) = v;
  }
  for (int q = tid; q < 8192; q += 512) {
    const int e = q >> 7, k = q & 127;
    const int row = n0 + e;
    const float v = (row < NN) ? agg_h[(size_t)row * 128 + k] : 0.f;
    buf[e * 264 + 128 + k] = f2b(v);
  }
  __syncthreads();

  f32x4 acc[4][4];
  #pragma unroll
  for (int i = 0; i < 4; i++)
    #pragma unroll
    for (int m = 0; m < 4; m++) acc[i][m] = {0.f, 0.f, 0.f, 0.f};
  for (int kt = 0; kt < 8; kt++) {
    bf16x8 af[4];
    #pragma unroll
    for (int m = 0; m < 4; m++)
      af[m] = *reinterpret_cast<const bf16x8*>(buf + (m * 16 + l_lo) * 264 + kt * 32 + l_hi * 8);
    #pragma unroll
    for (int i = 0; i < 4; i++) {
      const int nt = w + 8 * i;
      const bf16x8 bfr = *reinterpret_cast<const bf16x8*>(WN1s + (((nt * 8 + kt) << 6) + lane) * 8);
      #pragma unroll
      for (int m = 0; m < 4; m++)
        acc[i][m] = __builtin_amdgcn_mfma_f32_16x16x32_bf16(af[m], bfr, acc[i][m], 0, 0, 0);
    }
  }
  __syncthreads();
  #pragma unroll
  for (int i = 0; i < 4; i++) {
    const int nt = w + 8 * i;
    const int coln = nt * 16 + l_lo;
    const float bias = nb1[coln];
    #pragma unroll
    for (int m = 0; m < 4; m++)
      #pragma unroll
      for (int r = 0; r < 4; r++) {
        const int row = m * 16 + l_hi * 4 + r;
        buf[row * 520 + coln] = f2b(silu_f(acc[i][m][r] + bias));
      }
  }
  __syncthreads();

  f32x4 acc2[4];
  #pragma unroll
  for (int m = 0; m < 4; m++) acc2[m] = {0.f, 0.f, 0.f, 0.f};
  for (int kt = 0; kt < 16; kt++) {
    const bf16x8 bfr = *reinterpret_cast<const bf16x8*>(WN2s + (((w * 16 + kt) << 6) + lane) * 8);
    #pragma unroll
    for (int m = 0; m < 4; m++) {
      const bf16x8 af = *reinterpret_cast<const bf16x8*>(buf + (m * 16 + l_lo) * 520 + kt * 32 + l_hi * 8);
      acc2[m] = __builtin_amdgcn_mfma_f32_16x16x32_bf16(af, bfr, acc2[m], 0, 0, 0);
    }
  }
  {
    const int coln = w * 16 + l_lo;
    const float bias = nb2[coln];
    #pragma unroll
    for (int m = 0; m < 4; m++)
      #pragma unroll
      for (int r = 0; r < 4; r++) {
        const int row = n0 + m * 16 + l_hi * 4 + r;
        if (row < NN)
          out[(size_t)row * 128 + coln] = h[(size_t)row * 128 + coln] + silu_f(acc2[m][r] + bias);
      }
  }
}

__global__ void coord_kernel(const float* __restrict__ coord, const float* __restrict__ agg_c,
                             const float* __restrict__ cnt, float* __restrict__ out) {
  int i = blockIdx.x * 256 + threadIdx.x;
  if (i < NN * 9) {
    float c = fmaxf(cnt[i / 9], 1.f);
    float v = agg_c[i] / c;
    v = fminf(fmaxf(v, -10.f), 10.f);
    out[i] = coord[i] + v;
  }
}

extern "C" void kernel_launch(void* const* d_in, const int* in_sizes, int n_in,
                              void* d_out, int out_size, void* d_ws, size_t ws_size,
                              hipStream_t stream) {
  (void)in_sizes; (void)n_in; (void)out_size; (void)ws_size;
  const float* h     = (const float*)d_in[0];
  const int*   eidx  = (const int*)d_in[1];
  const float* coord = (const float*)d_in[2];
  const float* eW1 = (const float*)d_in[3];  const float* eb1 = (const float*)d_in[4];
  const float* eW2 = (const float*)d_in[5];  const float* eb2 = (const float*)d_in[6];
  const float* nW1 = (const float*)d_in[7];  const float* nb1 = (const float*)d_in[8];
  const float* nW2 = (const float*)d_in[9];  const float* nb2 = (const float*)d_in[10];
  const float* cW1 = (const float*)d_in[11]; const float* cb1 = (const float*)d_in[12];
  const float* cW2 = (const float*)d_in[13];

  char* ws = (char*)d_ws;
  u16* W1s  = (u16*)(ws + OFF_W1);
  u16* W2s  = (u16*)(ws + OFF_W2);
  u16* WC1s = (u16*)(ws + OFF_WC1);
  u16* WC2s = (u16*)(ws + OFF_WC2);
  u16* WN1s = (u16*)(ws + OFF_WN1);
  u16* WN2s = (u16*)(ws + OFF_WN2);
  u16* hb   = (u16*)(ws + OFF_HB);
  float* agg_h = (float*)(ws + OFF_AGGH);
  float* agg_c = (float*)(ws + OFF_AGGC);
  float* cnt   = (float*)(ws + OFF_CNT);
  float* out   = (float*)d_out;

  hipMemsetAsync(ws + OFF_AGGH, 0, SZ_AGGH + SZ_AGGC + SZ_CNT, stream);

  swz32_kernel<<<18 * 17 * 2, 256, 0, stream>>>(eW1, W1s, 265, 530, 18, 17);
  swz32_kernel<<<34 * 4 * 2, 256, 0, stream>>>(eW2, W2s, 530, 128, 34, 4);
  swz32_kernel<<<8 * 8 * 2, 256, 0, stream>>>(cW1, WC1s, 128, 256, 8, 8);
  swz32_kernel<<<16 * 1 * 2, 256, 0, stream>>>(cW2, WC2s, 256, 3, 16, 1);
  swz_kernel<<<8 * 32 * 2, 256, 0, stream>>>(nW1, WN1s, 256, 512, 8, 32);
  swz_kernel<<<16 * 8 * 2, 256, 0, stream>>>(nW2, WN2s, 512, 128, 16, 8);
  tob16_kernel<<<(NN * 128 + 255) / 256, 256, 0, stream>>>(h, hb, NN * 128);

  edge_kernel<<<NE / 64, 512, 0, stream>>>(hb, eidx, coord, W1s, eb1, W2s, eb2,
                                           WC1s, cb1, WC2s, agg_h, agg_c, cnt);
  node_kernel<<<(NN + 63) / 64, 512, 0, stream>>>(h, hb, agg_h, WN1s, nb1, WN2s, nb2, out);
  coord_kernel<<<(NN * 9 + 255) / 256, 256, 0, stream>>>(coord, agg_c, cnt, out + (size_t)NN * 128);
}

// Round 5
// 428.427 us; speedup vs baseline: 1.3217x; 1.0443x over previous
//
#include <hip/hip_runtime.h>
#include <hip/hip_bf16.h>

typedef unsigned short u16;
typedef __bf16 bf16x8 __attribute__((ext_vector_type(8)));
typedef float f32x4 __attribute__((ext_vector_type(4)));
typedef float f32x16 __attribute__((ext_vector_type(16)));

#define NN 20000
#define NE 320000

// ---------------- ws layout (bytes) ----------------
// 32x32-swizzled weights (edge pipeline)
constexpr size_t SZ_W1  = (size_t)18 * 17 * 512 * 2;  // eW1: K 288, N 544
constexpr size_t SZ_W2  = (size_t)34 * 4  * 512 * 2;  // eW2: K 544, N 128
constexpr size_t SZ_WC1 = (size_t)8  * 8  * 512 * 2;  // cW1: K 128, N 256
constexpr size_t SZ_WC2 = (size_t)16 * 1  * 512 * 2;  // cW2: K 256, N 32(3)
// 16x16-swizzled weights (node kernel)
constexpr size_t SZ_WN1 = (size_t)8  * 32 * 512 * 2;  // nW1: K 256, N 512
constexpr size_t SZ_WN2 = (size_t)16 * 8  * 512 * 2;  // nW2: K 512, N 128
constexpr size_t OFF_W1   = 0;
constexpr size_t OFF_W2   = OFF_W1 + SZ_W1;
constexpr size_t OFF_WC1  = OFF_W2 + SZ_W2;
constexpr size_t OFF_WC2  = OFF_WC1 + SZ_WC1;
constexpr size_t OFF_WN1  = OFF_WC2 + SZ_WC2;
constexpr size_t OFF_WN2  = OFF_WN1 + SZ_WN1;
constexpr size_t OFF_HB   = OFF_WN2 + SZ_WN2;         // h as bf16 [NN,128]
constexpr size_t SZ_HB    = (size_t)NN * 128 * 2;
constexpr size_t OFF_AGGH = OFF_HB + SZ_HB;           // f32 [NN,128]
constexpr size_t SZ_AGGH  = (size_t)NN * 128 * 4;
constexpr size_t OFF_AGGC = OFF_AGGH + SZ_AGGH;       // f32 [NN,9]
constexpr size_t SZ_AGGC  = (size_t)NN * 9 * 4;
constexpr size_t OFF_CNT  = OFF_AGGC + SZ_AGGC;       // f32 [NN]
constexpr size_t SZ_CNT   = (size_t)NN * 4;

__device__ __forceinline__ u16 f2b(float x) {
  union { float f; unsigned u; } v; v.f = x;
  unsigned r = (v.u + 0x7fffu + ((v.u >> 16) & 1u)) >> 16;
  return (u16)r;
}
__device__ __forceinline__ float silu_f(float x) {
  float e = __builtin_amdgcn_exp2f(-1.44269504088896f * x);
  return x * __builtin_amdgcn_rcpf(1.f + e);
}

// 16x16 B-fragment swizzle (node kernel weights)
__global__ void swz_kernel(const float* __restrict__ W, u16* __restrict__ dst,
                           int Kreal, int Nreal, int KT, int NT) {
  int idx = blockIdx.x * 256 + threadIdx.x;
  int total = KT * NT * 512;
  if (idx >= total) return;
  int e = idx & 7, l = (idx >> 3) & 63, blk = idx >> 9;
  int kt = blk % KT, nt = blk / KT;
  int k = kt * 32 + ((l >> 4) * 8) + e;
  int n = nt * 16 + (l & 15);
  float v = (k < Kreal && n < Nreal) ? W[(size_t)k * Nreal + n] : 0.f;
  dst[idx] = f2b(v);
}

// 32x32 B-fragment swizzle: dst[((nt*KT+kt)*64+l)*8+e] = W[kt*16+(l>>5)*8+e][nt*32+(l&31)]
__global__ void swz32_kernel(const float* __restrict__ W, u16* __restrict__ dst,
                             int Kreal, int Nreal, int KT, int NT) {
  int idx = blockIdx.x * 256 + threadIdx.x;
  int total = KT * NT * 512;
  if (idx >= total) return;
  int e = idx & 7, l = (idx >> 3) & 63, blk = idx >> 9;
  int kt = blk % KT, nt = blk / KT;
  int k = kt * 16 + ((l >> 5) * 8) + e;
  int n = nt * 32 + (l & 31);
  float v = (k < Kreal && n < Nreal) ? W[(size_t)k * Nreal + n] : 0.f;
  dst[idx] = f2b(v);
}

__global__ void tob16_kernel(const float* __restrict__ x, u16* __restrict__ y, int n) {
  int i = blockIdx.x * 256 + threadIdx.x;
  if (i < n) y[i] = f2b(x[i]);
}

// ---------------- fused edge pipeline: M=32, 4 waves, 32x32x16, 5 blocks/CU ----------------
// wave w = nh (n-group 0..3); m-tile rows = l5 (32 edges)
__global__ __launch_bounds__(256, 5)
void edge_kernel(const u16* __restrict__ hb, const int* __restrict__ eidx,
                 const float* __restrict__ coord,
                 const u16* __restrict__ W1s, const float* __restrict__ b1,
                 const u16* __restrict__ W2s, const float* __restrict__ b2,
                 const u16* __restrict__ WC1s, const float* __restrict__ bc1,
                 const u16* __restrict__ WC2s,
                 float* __restrict__ agg_h, float* __restrict__ agg_c,
                 float* __restrict__ cnt) {
  __shared__ __align__(16) u16 bufA[32 * 296];  // A1 [32][288+8] -> Y3 [32][264]
  __shared__ __align__(16) u16 bufB[32 * 136];  // Y1 chunk [32][128+8] -> ef [32][136]
  __shared__ float phi_s[32][4];
  __shared__ int row_s[32];

  const int tid = threadIdx.x;
  const int lane = tid & 63;
  const int nh = tid >> 6;
  const int l5 = lane & 31;
  const int hi = lane >> 5;
  const int e0 = blockIdx.x << 5;

  // gather h (all waves, eidx read directly) + radial (wave 0 lanes 0-31)
  for (int q = tid; q < 1024; q += 256) {
    const int e = q >> 5, sub = q & 31, which = sub >> 4, j = sub & 15;
    const int node = eidx[(which ? NE : 0) + e0 + e];
    const int4 v = *reinterpret_cast<const int4*>(hb + (size_t)node * 128 + j * 8);
    *reinterpret_cast<int4*>(bufA + e * 296 + which * 128 + j * 8) = v;
  }
  if (tid < 32) {
    const int r = eidx[e0 + tid], c = eidx[NE + e0 + tid];
    row_s[tid] = r;
    float cd[9];
    #pragma unroll
    for (int i = 0; i < 9; i++) cd[i] = coord[r * 9 + i] - coord[c * 9 + i];
    u16* arow = bufA + tid * 296;
    #pragma unroll
    for (int a = 0; a < 3; a++)
      #pragma unroll
      for (int b = 0; b < 3; b++) {
        float rad = cd[a*3]*cd[b*3] + cd[a*3+1]*cd[b*3+1] + cd[a*3+2]*cd[b*3+2];
        arow[256 + a * 3 + b] = f2b(rad);
      }
    #pragma unroll
    for (int k = 265; k < 288; k++) arow[k] = (u16)0;
  }
  __syncthreads();  // A1 + row_s ready

  // ---- chunked GEMM1 [32,288]x[288,544] -> silu -> GEMM2 [32,544]x[544,128] ----
  // chunk c (0..4): GEMM1 n-tile nt = c*4 + nh (valid < 17); bufB cols chunk-local (128)
  f32x16 acc2;
  #pragma unroll
  for (int t = 0; t < 16; t++) acc2[t] = 0.f;

  for (int c = 0; c < 5; c++) {
    const int nt = c * 4 + nh;
    f32x16 acc1;
    #pragma unroll
    for (int t = 0; t < 16; t++) acc1[t] = 0.f;

    if (nt < 17) {
      for (int kt = 0; kt < 18; kt++) {
        const bf16x8 af = *reinterpret_cast<const bf16x8*>(bufA + l5 * 296 + kt * 16 + hi * 8);
        const bf16x8 bw = *reinterpret_cast<const bf16x8*>(W1s + (((nt * 18 + kt) << 6) + lane) * 8);
        acc1 = __builtin_amdgcn_mfma_f32_32x32x16_bf16(af, bw, acc1, 0, 0, 0);
      }
    }
    __syncthreads();  // prev chunk's GEMM2 reads of bufB complete
    if (nt < 17) {
      const int colg = nt * 32 + l5;
      const float bias = (colg < 530) ? b1[colg] : 0.f;
      const int coll = nh * 32 + l5;
      #pragma unroll
      for (int r = 0; r < 16; r++) {
        const int rowi = (r & 3) + 8 * (r >> 2) + 4 * hi;
        bufB[rowi * 136 + coll] = f2b(silu_f(acc1[r] + bias));
      }
    }
    __syncthreads();  // Y1 chunk ready
    const int nk2 = (c < 4) ? 8 : 2;
    for (int k2 = 0; k2 < nk2; k2++) {
      const bf16x8 a = *reinterpret_cast<const bf16x8*>(bufB + l5 * 136 + k2 * 16 + hi * 8);
      const bf16x8 bw = *reinterpret_cast<const bf16x8*>(W2s + (((nh * 34 + c * 8 + k2) << 6) + lane) * 8);
      acc2 = __builtin_amdgcn_mfma_f32_32x32x16_bf16(a, bw, acc2, 0, 0, 0);
    }
  }
  __syncthreads();  // all GEMM2 reads of bufB done

  // ef = silu(acc2 + b2): keep in regs, write bf16 to bufB [32][136]
  f32x16 efv;
  {
    const int col = nh * 32 + l5;
    const float bias = b2[col];
    #pragma unroll
    for (int r = 0; r < 16; r++) {
      const int rowi = (r & 3) + 8 * (r >> 2) + 4 * hi;
      efv[r] = silu_f(acc2[r] + bias);
      bufB[rowi * 136 + col] = f2b(efv[r]);
    }
  }
  __syncthreads();  // ef ready

  // GEMM3: ef[32,128] x WC1[128,256]; wave nh: n-tiles nh*2+{0,1}
  f32x16 acc3[2];
  #pragma unroll
  for (int i = 0; i < 2; i++)
    #pragma unroll
    for (int t = 0; t < 16; t++) acc3[i][t] = 0.f;
  for (int kt = 0; kt < 8; kt++) {
    const bf16x8 a = *reinterpret_cast<const bf16x8*>(bufB + l5 * 136 + kt * 16 + hi * 8);
    #pragma unroll
    for (int i = 0; i < 2; i++) {
      const int nt = nh * 2 + i;
      const bf16x8 bw = *reinterpret_cast<const bf16x8*>(WC1s + (((nt * 8 + kt) << 6) + lane) * 8);
      acc3[i] = __builtin_amdgcn_mfma_f32_32x32x16_bf16(a, bw, acc3[i], 0, 0, 0);
    }
  }

  // agg_h atomics here: drain hides under GEMM3/epi3 instead of stalling a barrier
  {
    const int col = nh * 32 + l5;
    #pragma unroll
    for (int r = 0; r < 16; r++) {
      const int rowi = (r & 3) + 8 * (r >> 2) + 4 * hi;
      atomicAdd(&agg_h[(size_t)row_s[rowi] * 128 + col], efv[r]);
    }
  }

  // epi3 -> bufA as Y3 [32][264] (A1 fully consumed)
  #pragma unroll
  for (int i = 0; i < 2; i++) {
    const int col = (nh * 2 + i) * 32 + l5;
    const float bias = bc1[col];
    #pragma unroll
    for (int r = 0; r < 16; r++) {
      const int rowi = (r & 3) + 8 * (r >> 2) + 4 * hi;
      bufA[rowi * 264 + col] = f2b(silu_f(acc3[i][r] + bias));
    }
  }
  __syncthreads();  // Y3 ready (last barrier; waves 1-3 exit after this)

  // GEMM4 (wave 0 only): Y3[32,256] x WC2[256,32(3)]
  if (nh == 0) {
    f32x16 acc4;
    #pragma unroll
    for (int t = 0; t < 16; t++) acc4[t] = 0.f;
    for (int kt = 0; kt < 16; kt++) {
      const bf16x8 a = *reinterpret_cast<const bf16x8*>(bufA + l5 * 264 + kt * 16 + hi * 8);
      const bf16x8 bw = *reinterpret_cast<const bf16x8*>(WC2s + ((kt << 6) + lane) * 8);
      acc4 = __builtin_amdgcn_mfma_f32_32x32x16_bf16(a, bw, acc4, 0, 0, 0);
    }
    if (l5 < 3) {
      #pragma unroll
      for (int r = 0; r < 16; r++)
        phi_s[(r & 3) + 8 * (r >> 2) + 4 * hi][l5] = acc4[r];
    }
    // wave-internal LDS handoff: compiler inserts lgkmcnt wait, no barrier needed
    if (lane < 32) {
      const int r = row_s[lane], ci = eidx[NE + e0 + lane];
      float cd[9];
      #pragma unroll
      for (int i = 0; i < 9; i++) cd[i] = coord[r * 9 + i] - coord[ci * 9 + i];
      const float p0 = phi_s[lane][0], p1 = phi_s[lane][1], p2 = phi_s[lane][2];
      #pragma unroll
      for (int d = 0; d < 3; d++) {
        atomicAdd(&agg_c[(size_t)r * 9 + 0 + d], cd[0 + d] * p0);
        atomicAdd(&agg_c[(size_t)r * 9 + 3 + d], cd[3 + d] * p1);
        atomicAdd(&agg_c[(size_t)r * 9 + 6 + d], cd[6 + d] * p2);
      }
      atomicAdd(&cnt[r], 1.f);
    }
  }
}

// ---------------- node MLP (16x16 path) ----------------
__global__ __launch_bounds__(512)
void node_kernel(const float* __restrict__ h, const u16* __restrict__ hb,
                 const float* __restrict__ agg_h,
                 const u16* __restrict__ WN1s, const float* __restrict__ nb1,
                 const u16* __restrict__ WN2s, const float* __restrict__ nb2,
                 float* __restrict__ out) {
  __shared__ __align__(16) u16 buf[64 * 520];
  const int tid = threadIdx.x;
  const int lane = tid & 63;
  const int w = tid >> 6;
  const int l_lo = lane & 15;
  const int l_hi = lane >> 4;
  const int n0 = blockIdx.x << 6;

  for (int q = tid; q < 1024; q += 512) {
    const int e = q >> 4, j = q & 15;
    const int row = n0 + e;
    int4 v;
    if (row < NN) v = *reinterpret_cast<const int4*>(hb + (size_t)row * 128 + j * 8);
    else { v.x = v.y = v.z = v.w = 0; }
    *reinterpret_cast<int4*>(buf + e * 264 + j * 8) = v;
  }
  for (int q = tid; q < 8192; q += 512) {
    const int e = q >> 7, k = q & 127;
    const int row = n0 + e;
    const float v = (row < NN) ? agg_h[(size_t)row * 128 + k] : 0.f;
    buf[e * 264 + 128 + k] = f2b(v);
  }
  __syncthreads();

  f32x4 acc[4][4];
  #pragma unroll
  for (int i = 0; i < 4; i++)
    #pragma unroll
    for (int m = 0; m < 4; m++) acc[i][m] = {0.f, 0.f, 0.f, 0.f};
  for (int kt = 0; kt < 8; kt++) {
    bf16x8 af[4];
    #pragma unroll
    for (int m = 0; m < 4; m++)
      af[m] = *reinterpret_cast<const bf16x8*>(buf + (m * 16 + l_lo) * 264 + kt * 32 + l_hi * 8);
    #pragma unroll
    for (int i = 0; i < 4; i++) {
      const int nt = w + 8 * i;
      const bf16x8 bfr = *reinterpret_cast<const bf16x8*>(WN1s + (((nt * 8 + kt) << 6) + lane) * 8);
      #pragma unroll
      for (int m = 0; m < 4; m++)
        acc[i][m] = __builtin_amdgcn_mfma_f32_16x16x32_bf16(af[m], bfr, acc[i][m], 0, 0, 0);
    }
  }
  __syncthreads();
  #pragma unroll
  for (int i = 0; i < 4; i++) {
    const int nt = w + 8 * i;
    const int coln = nt * 16 + l_lo;
    const float bias = nb1[coln];
    #pragma unroll
    for (int m = 0; m < 4; m++)
      #pragma unroll
      for (int r = 0; r < 4; r++) {
        const int row = m * 16 + l_hi * 4 + r;
        buf[row * 520 + coln] = f2b(silu_f(acc[i][m][r] + bias));
      }
  }
  __syncthreads();

  f32x4 acc2[4];
  #pragma unroll
  for (int m = 0; m < 4; m++) acc2[m] = {0.f, 0.f, 0.f, 0.f};
  for (int kt = 0; kt < 16; kt++) {
    const bf16x8 bfr = *reinterpret_cast<const bf16x8*>(WN2s + (((w * 16 + kt) << 6) + lane) * 8);
    #pragma unroll
    for (int m = 0; m < 4; m++) {
      const bf16x8 af = *reinterpret_cast<const bf16x8*>(buf + (m * 16 + l_lo) * 520 + kt * 32 + l_hi * 8);
      acc2[m] = __builtin_amdgcn_mfma_f32_16x16x32_bf16(af, bfr, acc2[m], 0, 0, 0);
    }
  }
  {
    const int coln = w * 16 + l_lo;
    const float bias = nb2[coln];
    #pragma unroll
    for (int m = 0; m < 4; m++)
      #pragma unroll
      for (int r = 0; r < 4; r++) {
        const int row = n0 + m * 16 + l_hi * 4 + r;
        if (row < NN)
          out[(size_t)row * 128 + coln] = h[(size_t)row * 128 + coln] + silu_f(acc2[m][r] + bias);
      }
  }
}

__global__ void coord_kernel(const float* __restrict__ coord, const float* __restrict__ agg_c,
                             const float* __restrict__ cnt, float* __restrict__ out) {
  int i = blockIdx.x * 256 + threadIdx.x;
  if (i < NN * 9) {
    float c = fmaxf(cnt[i / 9], 1.f);
    float v = agg_c[i] / c;
    v = fminf(fmaxf(v, -10.f), 10.f);
    out[i] = coord[i] + v;
  }
}

extern "C" void kernel_launch(void* const* d_in, const int* in_sizes, int n_in,
                              void* d_out, int out_size, void* d_ws, size_t ws_size,
                              hipStream_t stream) {
  (void)in_sizes; (void)n_in; (void)out_size; (void)ws_size;
  const float* h     = (const float*)d_in[0];
  const int*   eidx  = (const int*)d_in[1];
  const float* coord = (const float*)d_in[2];
  const float* eW1 = (const float*)d_in[3];  const float* eb1 = (const float*)d_in[4];
  const float* eW2 = (const float*)d_in[5];  const float* eb2 = (const float*)d_in[6];
  const float* nW1 = (const float*)d_in[7];  const float* nb1 = (const float*)d_in[8];
  const float* nW2 = (const float*)d_in[9];  const float* nb2 = (const float*)d_in[10];
  const float* cW1 = (const float*)d_in[11]; const float* cb1 = (const float*)d_in[12];
  const float* cW2 = (const float*)d_in[13];

  char* ws = (char*)d_ws;
  u16* W1s  = (u16*)(ws + OFF_W1);
  u16* W2s  = (u16*)(ws + OFF_W2);
  u16* WC1s = (u16*)(ws + OFF_WC1);
  u16* WC2s = (u16*)(ws + OFF_WC2);
  u16* WN1s = (u16*)(ws + OFF_WN1);
  u16* WN2s = (u16*)(ws + OFF_WN2);
  u16* hb   = (u16*)(ws + OFF_HB);
  float* agg_h = (float*)(ws + OFF_AGGH);
  float* agg_c = (float*)(ws + OFF_AGGC);
  float* cnt   = (float*)(ws + OFF_CNT);
  float* out   = (float*)d_out;

  hipMemsetAsync(ws + OFF_AGGH, 0, SZ_AGGH + SZ_AGGC + SZ_CNT, stream);

  swz32_kernel<<<18 * 17 * 2, 256, 0, stream>>>(eW1, W1s, 265, 530, 18, 17);
  swz32_kernel<<<34 * 4 * 2, 256, 0, stream>>>(eW2, W2s, 530, 128, 34, 4);
  swz32_kernel<<<8 * 8 * 2, 256, 0, stream>>>(cW1, WC1s, 128, 256, 8, 8);
  swz32_kernel<<<16 * 1 * 2, 256, 0, stream>>>(cW2, WC2s, 256, 3, 16, 1);
  swz_kernel<<<8 * 32 * 2, 256, 0, stream>>>(nW1, WN1s, 256, 512, 8, 32);
  swz_kernel<<<16 * 8 * 2, 256, 0, stream>>>(nW2, WN2s, 512, 128, 16, 8);
  tob16_kernel<<<(NN * 128 + 255) / 256, 256, 0, stream>>>(h, hb, NN * 128);

  edge_kernel<<<NE / 32, 256, 0, stream>>>(hb, eidx, coord, W1s, eb1, W2s, eb2,
                                           WC1s, cb1, WC2s, agg_h, agg_c, cnt);
  node_kernel<<<(NN + 63) / 64, 512, 0, stream>>>(h, hb, agg_h, WN1s, nb1, WN2s, nb2, out);
  coord_kernel<<<(NN * 9 + 255) / 256, 256, 0, stream>>>(coord, agg_c, cnt, out + (size_t)NN * 128);
}

// Round 6
// 384.144 us; speedup vs baseline: 1.4741x; 1.1153x over previous
//
#include <hip/hip_runtime.h>
#include <hip/hip_bf16.h>

typedef unsigned short u16;
typedef __bf16 bf16x8 __attribute__((ext_vector_type(8)));
typedef float f32x4 __attribute__((ext_vector_type(4)));
typedef float f32x16 __attribute__((ext_vector_type(16)));

#define NN 20000
#define NE 320000

// ---------------- ws layout (bytes) ----------------
// 32x32-swizzled weights (edge pipeline)
constexpr size_t SZ_W1  = (size_t)18 * 17 * 512 * 2;  // eW1: K 288, N 544
constexpr size_t SZ_W2  = (size_t)34 * 4  * 512 * 2;  // eW2: K 544, N 128
constexpr size_t SZ_WC1 = (size_t)8  * 8  * 512 * 2;  // cW1: K 128, N 256
constexpr size_t SZ_WC2 = (size_t)16 * 1  * 512 * 2;  // cW2: K 256, N 32(3)
// 16x16-swizzled weights (node kernel)
constexpr size_t SZ_WN1 = (size_t)8  * 32 * 512 * 2;  // nW1: K 256, N 512
constexpr size_t SZ_WN2 = (size_t)16 * 8  * 512 * 2;  // nW2: K 512, N 128
constexpr size_t OFF_W1   = 0;
constexpr size_t OFF_W2   = OFF_W1 + SZ_W1;
constexpr size_t OFF_WC1  = OFF_W2 + SZ_W2;
constexpr size_t OFF_WC2  = OFF_WC1 + SZ_WC1;
constexpr size_t OFF_WN1  = OFF_WC2 + SZ_WC2;
constexpr size_t OFF_WN2  = OFF_WN1 + SZ_WN1;
constexpr size_t OFF_HB   = OFF_WN2 + SZ_WN2;         // h as bf16 [NN,128]
constexpr size_t SZ_HB    = (size_t)NN * 128 * 2;
constexpr size_t OFF_AGGH = OFF_HB + SZ_HB;           // bf16 [NN,128]
constexpr size_t SZ_AGGH  = (size_t)NN * 128 * 2;
constexpr size_t OFF_AGGC = OFF_AGGH + SZ_AGGH;       // f32 [NN,9]
constexpr size_t SZ_AGGC  = (size_t)NN * 9 * 4;
constexpr size_t OFF_CNT  = OFF_AGGC + SZ_AGGC;       // f32 [NN]
constexpr size_t SZ_CNT   = (size_t)NN * 4;

__device__ __forceinline__ u16 f2b(float x) {
  union { float f; unsigned u; } v; v.f = x;
  unsigned r = (v.u + 0x7fffu + ((v.u >> 16) & 1u)) >> 16;
  return (u16)r;
}
__device__ __forceinline__ float b2f(unsigned b) {
  union { unsigned u; float f; } v; v.u = b << 16; return v.f;
}
__device__ __forceinline__ float silu_f(float x) {
  float e = __builtin_amdgcn_exp2f(-1.44269504088896f * x);
  return x * __builtin_amdgcn_rcpf(1.f + e);
}

// packed bf16 atomic add of (a -> p[0], b -> p[1])
__device__ __forceinline__ void pk_atomic_bf16(u16* p, float a, float b) {
#if __has_builtin(__builtin_amdgcn_global_atomic_fadd_v2bf16)
  typedef short v2s __attribute__((ext_vector_type(2)));
  v2s v; v[0] = (short)f2b(a); v[1] = (short)f2b(b);
  __builtin_amdgcn_global_atomic_fadd_v2bf16((v2s*)p, v);
#else
  unsigned* q = (unsigned*)p;
  unsigned old = *q, assumed;
  do {
    assumed = old;
    float lo = b2f(assumed & 0xffffu) + a;
    float hi = b2f(assumed >> 16) + b;
    unsigned nv = (unsigned)f2b(lo) | ((unsigned)f2b(hi) << 16);
    old = atomicCAS(q, assumed, nv);
  } while (old != assumed);
#endif
}

// 16x16 B-fragment swizzle (node kernel weights)
__global__ void swz_kernel(const float* __restrict__ W, u16* __restrict__ dst,
                           int Kreal, int Nreal, int KT, int NT) {
  int idx = blockIdx.x * 256 + threadIdx.x;
  int total = KT * NT * 512;
  if (idx >= total) return;
  int e = idx & 7, l = (idx >> 3) & 63, blk = idx >> 9;
  int kt = blk % KT, nt = blk / KT;
  int k = kt * 32 + ((l >> 4) * 8) + e;
  int n = nt * 16 + (l & 15);
  float v = (k < Kreal && n < Nreal) ? W[(size_t)k * Nreal + n] : 0.f;
  dst[idx] = f2b(v);
}

// 32x32 B-fragment swizzle: dst[((nt*KT+kt)*64+l)*8+e] = W[kt*16+(l>>5)*8+e][nt*32+(l&31)]
__global__ void swz32_kernel(const float* __restrict__ W, u16* __restrict__ dst,
                             int Kreal, int Nreal, int KT, int NT) {
  int idx = blockIdx.x * 256 + threadIdx.x;
  int total = KT * NT * 512;
  if (idx >= total) return;
  int e = idx & 7, l = (idx >> 3) & 63, blk = idx >> 9;
  int kt = blk % KT, nt = blk / KT;
  int k = kt * 16 + ((l >> 5) * 8) + e;
  int n = nt * 32 + (l & 31);
  float v = (k < Kreal && n < Nreal) ? W[(size_t)k * Nreal + n] : 0.f;
  dst[idx] = f2b(v);
}

__global__ void tob16_kernel(const float* __restrict__ x, u16* __restrict__ y, int n) {
  int i = blockIdx.x * 256 + threadIdx.x;
  if (i < n) y[i] = f2b(x[i]);
}

// ---------------- fused edge pipeline: M=32, 4 waves, 32x32x16, 5 blocks/CU ----------------
__global__ __launch_bounds__(256, 5)
void edge_kernel(const u16* __restrict__ hb, const int* __restrict__ eidx,
                 const float* __restrict__ coord,
                 const u16* __restrict__ W1s, const float* __restrict__ b1,
                 const u16* __restrict__ W2s, const float* __restrict__ b2,
                 const u16* __restrict__ WC1s, const float* __restrict__ bc1,
                 const u16* __restrict__ WC2s,
                 u16* __restrict__ agg_h, float* __restrict__ agg_c,
                 float* __restrict__ cnt) {
  __shared__ __align__(16) u16 bufA[32 * 296];  // A1 [32][288+8] -> Y3 [32][264]
  __shared__ __align__(16) u16 bufB[32 * 136];  // Y1 chunk [32][128+8] -> ef [32][136]
  __shared__ float phi_s[32][4];
  __shared__ int row_s[32];

  const int tid = threadIdx.x;
  const int lane = tid & 63;
  const int nh = tid >> 6;
  const int l5 = lane & 31;
  const int hi = lane >> 5;
  const int e0 = blockIdx.x << 5;

  // gather h (all waves, eidx read directly) + radial (wave 0 lanes 0-31)
  for (int q = tid; q < 1024; q += 256) {
    const int e = q >> 5, sub = q & 31, which = sub >> 4, j = sub & 15;
    const int node = eidx[(which ? NE : 0) + e0 + e];
    const int4 v = *reinterpret_cast<const int4*>(hb + (size_t)node * 128 + j * 8);
    *reinterpret_cast<int4*>(bufA + e * 296 + which * 128 + j * 8) = v;
  }
  if (tid < 32) {
    const int r = eidx[e0 + tid], c = eidx[NE + e0 + tid];
    row_s[tid] = r;
    float cd[9];
    #pragma unroll
    for (int i = 0; i < 9; i++) cd[i] = coord[r * 9 + i] - coord[c * 9 + i];
    u16* arow = bufA + tid * 296;
    #pragma unroll
    for (int a = 0; a < 3; a++)
      #pragma unroll
      for (int b = 0; b < 3; b++) {
        float rad = cd[a*3]*cd[b*3] + cd[a*3+1]*cd[b*3+1] + cd[a*3+2]*cd[b*3+2];
        arow[256 + a * 3 + b] = f2b(rad);
      }
    #pragma unroll
    for (int k = 265; k < 288; k++) arow[k] = (u16)0;
  }
  __syncthreads();  // A1 + row_s ready

  // ---- chunked GEMM1 [32,288]x[288,544] -> silu -> GEMM2 [32,544]x[544,128] ----
  f32x16 acc2;
  #pragma unroll
  for (int t = 0; t < 16; t++) acc2[t] = 0.f;

  for (int c = 0; c < 5; c++) {
    const int nt = c * 4 + nh;
    f32x16 acc1;
    #pragma unroll
    for (int t = 0; t < 16; t++) acc1[t] = 0.f;

    if (nt < 17) {
      for (int kt = 0; kt < 18; kt++) {
        const bf16x8 af = *reinterpret_cast<const bf16x8*>(bufA + l5 * 296 + kt * 16 + hi * 8);
        const bf16x8 bw = *reinterpret_cast<const bf16x8*>(W1s + (((nt * 18 + kt) << 6) + lane) * 8);
        acc1 = __builtin_amdgcn_mfma_f32_32x32x16_bf16(af, bw, acc1, 0, 0, 0);
      }
    }
    __syncthreads();  // prev chunk's GEMM2 reads of bufB complete
    if (nt < 17) {
      const int colg = nt * 32 + l5;
      const float bias = (colg < 530) ? b1[colg] : 0.f;
      const int coll = nh * 32 + l5;
      #pragma unroll
      for (int r = 0; r < 16; r++) {
        const int rowi = (r & 3) + 8 * (r >> 2) + 4 * hi;
        bufB[rowi * 136 + coll] = f2b(silu_f(acc1[r] + bias));
      }
    }
    __syncthreads();  // Y1 chunk ready
    const int nk2 = (c < 4) ? 8 : 2;
    for (int k2 = 0; k2 < nk2; k2++) {
      const bf16x8 a = *reinterpret_cast<const bf16x8*>(bufB + l5 * 136 + k2 * 16 + hi * 8);
      const bf16x8 bw = *reinterpret_cast<const bf16x8*>(W2s + (((nh * 34 + c * 8 + k2) << 6) + lane) * 8);
      acc2 = __builtin_amdgcn_mfma_f32_32x32x16_bf16(a, bw, acc2, 0, 0, 0);
    }
  }
  __syncthreads();  // all GEMM2 reads of bufB done

  // ef = silu(acc2 + b2): keep in regs, write bf16 to bufB [32][136]
  f32x16 efv;
  {
    const int col = nh * 32 + l5;
    const float bias = b2[col];
    #pragma unroll
    for (int r = 0; r < 16; r++) {
      const int rowi = (r & 3) + 8 * (r >> 2) + 4 * hi;
      efv[r] = silu_f(acc2[r] + bias);
      bufB[rowi * 136 + col] = f2b(efv[r]);
    }
  }
  __syncthreads();  // ef ready

  // GEMM3: ef[32,128] x WC1[128,256]; wave nh: n-tiles nh*2+{0,1}
  f32x16 acc3[2];
  #pragma unroll
  for (int i = 0; i < 2; i++)
    #pragma unroll
    for (int t = 0; t < 16; t++) acc3[i][t] = 0.f;
  for (int kt = 0; kt < 8; kt++) {
    const bf16x8 a = *reinterpret_cast<const bf16x8*>(bufB + l5 * 136 + kt * 16 + hi * 8);
    #pragma unroll
    for (int i = 0; i < 2; i++) {
      const int nt = nh * 2 + i;
      const bf16x8 bw = *reinterpret_cast<const bf16x8*>(WC1s + (((nt * 8 + kt) << 6) + lane) * 8);
      acc3[i] = __builtin_amdgcn_mfma_f32_32x32x16_bf16(a, bw, acc3[i], 0, 0, 0);
    }
  }

  // agg_h packed-bf16 atomics: lane pairs (l5 even/odd) -> one v2bf16 RMW per 2 cols.
  // Drain hides under epi3; halves atomic lane-ops and bytes vs f32.
  {
    const int col = nh * 32 + l5;
    #pragma unroll
    for (int r = 0; r < 16; r++) {
      const float other = __shfl_xor(efv[r], 1);
      if ((l5 & 1) == 0) {
        const int rowi = (r & 3) + 8 * (r >> 2) + 4 * hi;
        pk_atomic_bf16(agg_h + (size_t)row_s[rowi] * 128 + col, efv[r], other);
      }
    }
  }

  // epi3 -> bufA as Y3 [32][264] (A1 fully consumed)
  #pragma unroll
  for (int i = 0; i < 2; i++) {
    const int col = (nh * 2 + i) * 32 + l5;
    const float bias = bc1[col];
    #pragma unroll
    for (int r = 0; r < 16; r++) {
      const int rowi = (r & 3) + 8 * (r >> 2) + 4 * hi;
      bufA[rowi * 264 + col] = f2b(silu_f(acc3[i][r] + bias));
    }
  }
  __syncthreads();  // Y3 ready

  // GEMM4 (wave 0 only): Y3[32,256] x WC2[256,32(3)]
  if (nh == 0) {
    f32x16 acc4;
    #pragma unroll
    for (int t = 0; t < 16; t++) acc4[t] = 0.f;
    for (int kt = 0; kt < 16; kt++) {
      const bf16x8 a = *reinterpret_cast<const bf16x8*>(bufA + l5 * 264 + kt * 16 + hi * 8);
      const bf16x8 bw = *reinterpret_cast<const bf16x8*>(WC2s + ((kt << 6) + lane) * 8);
      acc4 = __builtin_amdgcn_mfma_f32_32x32x16_bf16(a, bw, acc4, 0, 0, 0);
    }
    if (l5 < 3) {
      #pragma unroll
      for (int r = 0; r < 16; r++)
        phi_s[(r & 3) + 8 * (r >> 2) + 4 * hi][l5] = acc4[r];
    }
    if (lane < 32) {
      const int r = row_s[lane], ci = eidx[NE + e0 + lane];
      float cd[9];
      #pragma unroll
      for (int i = 0; i < 9; i++) cd[i] = coord[r * 9 + i] - coord[ci * 9 + i];
      const float p0 = phi_s[lane][0], p1 = phi_s[lane][1], p2 = phi_s[lane][2];
      #pragma unroll
      for (int d = 0; d < 3; d++) {
        atomicAdd(&agg_c[(size_t)r * 9 + 0 + d], cd[0 + d] * p0);
        atomicAdd(&agg_c[(size_t)r * 9 + 3 + d], cd[3 + d] * p1);
        atomicAdd(&agg_c[(size_t)r * 9 + 6 + d], cd[6 + d] * p2);
      }
      atomicAdd(&cnt[r], 1.f);
    }
  }
}

// ---------------- node MLP (16x16 path; agg_h now bf16) ----------------
__global__ __launch_bounds__(512)
void node_kernel(const float* __restrict__ h, const u16* __restrict__ hb,
                 const u16* __restrict__ aggh,
                 const u16* __restrict__ WN1s, const float* __restrict__ nb1,
                 const u16* __restrict__ WN2s, const float* __restrict__ nb2,
                 float* __restrict__ out) {
  __shared__ __align__(16) u16 buf[64 * 520];
  const int tid = threadIdx.x;
  const int lane = tid & 63;
  const int w = tid >> 6;
  const int l_lo = lane & 15;
  const int l_hi = lane >> 4;
  const int n0 = blockIdx.x << 6;

  for (int q = tid; q < 2048; q += 512) {
    const int e = q >> 5, sub = q & 31, which = sub >> 4, j = sub & 15;
    const int row = n0 + e;
    const u16* src = which ? aggh : hb;
    int4 v;
    if (row < NN) v = *reinterpret_cast<const int4*>(src + (size_t)row * 128 + j * 8);
    else { v.x = v.y = v.z = v.w = 0; }
    *reinterpret_cast<int4*>(buf + e * 264 + which * 128 + j * 8) = v;
  }
  __syncthreads();

  f32x4 acc[4][4];
  #pragma unroll
  for (int i = 0; i < 4; i++)
    #pragma unroll
    for (int m = 0; m < 4; m++) acc[i][m] = {0.f, 0.f, 0.f, 0.f};
  for (int kt = 0; kt < 8; kt++) {
    bf16x8 af[4];
    #pragma unroll
    for (int m = 0; m < 4; m++)
      af[m] = *reinterpret_cast<const bf16x8*>(buf + (m * 16 + l_lo) * 264 + kt * 32 + l_hi * 8);
    #pragma unroll
    for (int i = 0; i < 4; i++) {
      const int nt = w + 8 * i;
      const bf16x8 bfr = *reinterpret_cast<const bf16x8*>(WN1s + (((nt * 8 + kt) << 6) + lane) * 8);
      #pragma unroll
      for (int m = 0; m < 4; m++)
        acc[i][m] = __builtin_amdgcn_mfma_f32_16x16x32_bf16(af[m], bfr, acc[i][m], 0, 0, 0);
    }
  }
  __syncthreads();
  #pragma unroll
  for (int i = 0; i < 4; i++) {
    const int nt = w + 8 * i;
    const int coln = nt * 16 + l_lo;
    const float bias = nb1[coln];
    #pragma unroll
    for (int m = 0; m < 4; m++)
      #pragma unroll
      for (int r = 0; r < 4; r++) {
        const int row = m * 16 + l_hi * 4 + r;
        buf[row * 520 + coln] = f2b(silu_f(acc[i][m][r] + bias));
      }
  }
  __syncthreads();

  f32x4 acc2[4];
  #pragma unroll
  for (int m = 0; m < 4; m++) acc2[m] = {0.f, 0.f, 0.f, 0.f};
  for (int kt = 0; kt < 16; kt++) {
    const bf16x8 bfr = *reinterpret_cast<const bf16x8*>(WN2s + (((w * 16 + kt) << 6) + lane) * 8);
    #pragma unroll
    for (int m = 0; m < 4; m++) {
      const bf16x8 af = *reinterpret_cast<const bf16x8*>(buf + (m * 16 + l_lo) * 520 + kt * 32 + l_hi * 8);
      acc2[m] = __builtin_amdgcn_mfma_f32_16x16x32_bf16(af, bfr, acc2[m], 0, 0, 0);
    }
  }
  {
    const int coln = w * 16 + l_lo;
    const float bias = nb2[coln];
    #pragma unroll
    for (int m = 0; m < 4; m++)
      #pragma unroll
      for (int r = 0; r < 4; r++) {
        const int row = n0 + m * 16 + l_hi * 4 + r;
        if (row < NN)
          out[(size_t)row * 128 + coln] = h[(size_t)row * 128 + coln] + silu_f(acc2[m][r] + bias);
      }
  }
}

__global__ void coord_kernel(const float* __restrict__ coord, const float* __restrict__ agg_c,
                             const float* __restrict__ cnt, float* __restrict__ out) {
  int i = blockIdx.x * 256 + threadIdx.x;
  if (i < NN * 9) {
    float c = fmaxf(cnt[i / 9], 1.f);
    float v = agg_c[i] / c;
    v = fminf(fmaxf(v, -10.f), 10.f);
    out[i] = coord[i] + v;
  }
}

extern "C" void kernel_launch(void* const* d_in, const int* in_sizes, int n_in,
                              void* d_out, int out_size, void* d_ws, size_t ws_size,
                              hipStream_t stream) {
  (void)in_sizes; (void)n_in; (void)out_size; (void)ws_size;
  const float* h     = (const float*)d_in[0];
  const int*   eidx  = (const int*)d_in[1];
  const float* coord = (const float*)d_in[2];
  const float* eW1 = (const float*)d_in[3];  const float* eb1 = (const float*)d_in[4];
  const float* eW2 = (const float*)d_in[5];  const float* eb2 = (const float*)d_in[6];
  const float* nW1 = (const float*)d_in[7];  const float* nb1 = (const float*)d_in[8];
  const float* nW2 = (const float*)d_in[9];  const float* nb2 = (const float*)d_in[10];
  const float* cW1 = (const float*)d_in[11]; const float* cb1 = (const float*)d_in[12];
  const float* cW2 = (const float*)d_in[13];

  char* ws = (char*)d_ws;
  u16* W1s  = (u16*)(ws + OFF_W1);
  u16* W2s  = (u16*)(ws + OFF_W2);
  u16* WC1s = (u16*)(ws + OFF_WC1);
  u16* WC2s = (u16*)(ws + OFF_WC2);
  u16* WN1s = (u16*)(ws + OFF_WN1);
  u16* WN2s = (u16*)(ws + OFF_WN2);
  u16* hb   = (u16*)(ws + OFF_HB);
  u16* agg_h  = (u16*)(ws + OFF_AGGH);
  float* agg_c = (float*)(ws + OFF_AGGC);
  float* cnt   = (float*)(ws + OFF_CNT);
  float* out   = (float*)d_out;

  hipMemsetAsync(ws + OFF_AGGH, 0, SZ_AGGH + SZ_AGGC + SZ_CNT, stream);

  swz32_kernel<<<18 * 17 * 2, 256, 0, stream>>>(eW1, W1s, 265, 530, 18, 17);
  swz32_kernel<<<34 * 4 * 2, 256, 0, stream>>>(eW2, W2s, 530, 128, 34, 4);
  swz32_kernel<<<8 * 8 * 2, 256, 0, stream>>>(cW1, WC1s, 128, 256, 8, 8);
  swz32_kernel<<<16 * 1 * 2, 256, 0, stream>>>(cW2, WC2s, 256, 3, 16, 1);
  swz_kernel<<<8 * 32 * 2, 256, 0, stream>>>(nW1, WN1s, 256, 512, 8, 32);
  swz_kernel<<<16 * 8 * 2, 256, 0, stream>>>(nW2, WN2s, 512, 128, 16, 8);
  tob16_kernel<<<(NN * 128 + 255) / 256, 256, 0, stream>>>(h, hb, NN * 128);

  edge_kernel<<<NE / 32, 256, 0, stream>>>(hb, eidx, coord, W1s, eb1, W2s, eb2,
                                           WC1s, cb1, WC2s, agg_h, agg_c, cnt);
  node_kernel<<<(NN + 63) / 64, 512, 0, stream>>>(h, hb, agg_h, WN1s, nb1, WN2s, nb2, out);
  coord_kernel<<<(NN * 9 + 255) / 256, 256, 0, stream>>>(coord, agg_c, cnt, out + (size_t)NN * 128);
}

// Round 7
// 375.215 us; speedup vs baseline: 1.5091x; 1.0238x over previous
//
#include <hip/hip_runtime.h>
#include <hip/hip_bf16.h>

typedef unsigned short u16;
typedef __bf16 bf16x8 __attribute__((ext_vector_type(8)));
typedef float f32x4 __attribute__((ext_vector_type(4)));
typedef float f32x16 __attribute__((ext_vector_type(16)));

#define NN 20000
#define NE 320000

// ---------------- ws layout (bytes) ----------------
constexpr size_t SZ_W1  = (size_t)18 * 17 * 512 * 2;  // eW1: K 288, N 544
constexpr size_t SZ_W2  = (size_t)34 * 4  * 512 * 2;  // eW2: K 544, N 128
constexpr size_t SZ_WC1 = (size_t)8  * 8  * 512 * 2;  // cW1: K 128, N 256
constexpr size_t SZ_WC2 = (size_t)16 * 1  * 512 * 2;  // cW2: K 256, N 32(3)
constexpr size_t SZ_WN1 = (size_t)8  * 32 * 512 * 2;  // nW1: K 256, N 512
constexpr size_t SZ_WN2 = (size_t)16 * 8  * 512 * 2;  // nW2: K 512, N 128
constexpr size_t OFF_W1   = 0;
constexpr size_t OFF_W2   = OFF_W1 + SZ_W1;
constexpr size_t OFF_WC1  = OFF_W2 + SZ_W2;
constexpr size_t OFF_WC2  = OFF_WC1 + SZ_WC1;
constexpr size_t OFF_WN1  = OFF_WC2 + SZ_WC2;
constexpr size_t OFF_WN2  = OFF_WN1 + SZ_WN1;
constexpr size_t OFF_HB   = OFF_WN2 + SZ_WN2;         // h as bf16 [NN,128]
constexpr size_t SZ_HB    = (size_t)NN * 128 * 2;
constexpr size_t OFF_AGGH = OFF_HB + SZ_HB;           // bf16 [NN,128]
constexpr size_t SZ_AGGH  = (size_t)NN * 128 * 2;
constexpr size_t OFF_AGGC = OFF_AGGH + SZ_AGGH;       // f32 [NN,9]
constexpr size_t SZ_AGGC  = (size_t)NN * 9 * 4;
constexpr size_t OFF_CNT  = OFF_AGGC + SZ_AGGC;       // f32 [NN]
constexpr size_t SZ_CNT   = (size_t)NN * 4;

__device__ __forceinline__ u16 f2b(float x) {
  union { float f; unsigned u; } v; v.f = x;
  unsigned r = (v.u + 0x7fffu + ((v.u >> 16) & 1u)) >> 16;
  return (u16)r;
}
__device__ __forceinline__ float b2f(unsigned b) {
  union { unsigned u; float f; } v; v.u = b << 16; return v.f;
}
__device__ __forceinline__ float silu_f(float x) {
  float e = __builtin_amdgcn_exp2f(-1.44269504088896f * x);
  return x * __builtin_amdgcn_rcpf(1.f + e);
}

__device__ __forceinline__ void pk_atomic_bf16(u16* p, float a, float b) {
#if __has_builtin(__builtin_amdgcn_global_atomic_fadd_v2bf16)
  typedef short v2s __attribute__((ext_vector_type(2)));
  v2s v; v[0] = (short)f2b(a); v[1] = (short)f2b(b);
  __builtin_amdgcn_global_atomic_fadd_v2bf16((v2s*)p, v);
#else
  unsigned* q = (unsigned*)p;
  unsigned old = *q, assumed;
  do {
    assumed = old;
    float lo = b2f(assumed & 0xffffu) + a;
    float hi = b2f(assumed >> 16) + b;
    unsigned nv = (unsigned)f2b(lo) | ((unsigned)f2b(hi) << 16);
    old = atomicCAS(q, assumed, nv);
  } while (old != assumed);
#endif
}

// 16x16 B-fragment swizzle (node kernel weights)
__global__ void swz_kernel(const float* __restrict__ W, u16* __restrict__ dst,
                           int Kreal, int Nreal, int KT, int NT) {
  int idx = blockIdx.x * 256 + threadIdx.x;
  int total = KT * NT * 512;
  if (idx >= total) return;
  int e = idx & 7, l = (idx >> 3) & 63, blk = idx >> 9;
  int kt = blk % KT, nt = blk / KT;
  int k = kt * 32 + ((l >> 4) * 8) + e;
  int n = nt * 16 + (l & 15);
  float v = (k < Kreal && n < Nreal) ? W[(size_t)k * Nreal + n] : 0.f;
  dst[idx] = f2b(v);
}

// 32x32 B-fragment swizzle
__global__ void swz32_kernel(const float* __restrict__ W, u16* __restrict__ dst,
                             int Kreal, int Nreal, int KT, int NT) {
  int idx = blockIdx.x * 256 + threadIdx.x;
  int total = KT * NT * 512;
  if (idx >= total) return;
  int e = idx & 7, l = (idx >> 3) & 63, blk = idx >> 9;
  int kt = blk % KT, nt = blk / KT;
  int k = kt * 16 + ((l >> 5) * 8) + e;
  int n = nt * 32 + (l & 31);
  float v = (k < Kreal && n < Nreal) ? W[(size_t)k * Nreal + n] : 0.f;
  dst[idx] = f2b(v);
}

__global__ void tob16_kernel(const float* __restrict__ x, u16* __restrict__ y, int n) {
  int i = blockIdx.x * 256 + threadIdx.x;
  if (i < n) y[i] = f2b(x[i]);
}

// ---------------- fused edge pipeline: M=32, 4 waves, 32x32x16, 5 blocks/CU ----------------
// Round-7 change: every GEMM k-loop uses a rolling register FIFO of prefetched
// B-fragments (distance 4-6), fully unrolled so FIFO indices are static.
__global__ __launch_bounds__(256, 5)
void edge_kernel(const u16* __restrict__ hb, const int* __restrict__ eidx,
                 const float* __restrict__ coord,
                 const u16* __restrict__ W1s, const float* __restrict__ b1,
                 const u16* __restrict__ W2s, const float* __restrict__ b2,
                 const u16* __restrict__ WC1s, const float* __restrict__ bc1,
                 const u16* __restrict__ WC2s,
                 u16* __restrict__ agg_h, float* __restrict__ agg_c,
                 float* __restrict__ cnt) {
  __shared__ __align__(16) u16 bufA[32 * 296];  // A1 [32][288+8] -> Y3 [32][264]
  __shared__ __align__(16) u16 bufB[32 * 136];  // Y1 chunk [32][128+8] -> ef [32][136]
  __shared__ float phi_s[32][4];
  __shared__ int row_s[32];

  const int tid = threadIdx.x;
  const int lane = tid & 63;
  const int nh = tid >> 6;
  const int l5 = lane & 31;
  const int hi = lane >> 5;
  const int e0 = blockIdx.x << 5;

  // gather h (all waves) + radial (wave 0 lanes 0-31)
  for (int q = tid; q < 1024; q += 256) {
    const int e = q >> 5, sub = q & 31, which = sub >> 4, j = sub & 15;
    const int node = eidx[(which ? NE : 0) + e0 + e];
    const int4 v = *reinterpret_cast<const int4*>(hb + (size_t)node * 128 + j * 8);
    *reinterpret_cast<int4*>(bufA + e * 296 + which * 128 + j * 8) = v;
  }
  if (tid < 32) {
    const int r = eidx[e0 + tid], c = eidx[NE + e0 + tid];
    row_s[tid] = r;
    float cd[9];
    #pragma unroll
    for (int i = 0; i < 9; i++) cd[i] = coord[r * 9 + i] - coord[c * 9 + i];
    u16* arow = bufA + tid * 296;
    #pragma unroll
    for (int a = 0; a < 3; a++)
      #pragma unroll
      for (int b = 0; b < 3; b++) {
        float rad = cd[a*3]*cd[b*3] + cd[a*3+1]*cd[b*3+1] + cd[a*3+2]*cd[b*3+2];
        arow[256 + a * 3 + b] = f2b(rad);
      }
    #pragma unroll
    for (int k = 265; k < 288; k++) arow[k] = (u16)0;
  }
  __syncthreads();  // A1 + row_s ready

  // ---- chunked GEMM1 [32,288]x[288,544] -> silu -> GEMM2 [32,544]x[544,128] ----
  f32x16 acc2;
  #pragma unroll
  for (int t = 0; t < 16; t++) acc2[t] = 0.f;

  #pragma unroll
  for (int c = 0; c < 5; c++) {
    const int nt = c * 4 + nh;
    const bool act = (nt < 17);
    f32x16 acc1;
    #pragma unroll
    for (int t = 0; t < 16; t++) acc1[t] = 0.f;

    if (act) {
      // rolling FIFO distance 6 over 18 k-steps
      const u16* bp = W1s + ((((nt * 18) << 6) + lane) << 3);
      bf16x8 bq[6];
      #pragma unroll
      for (int j = 0; j < 6; j++) bq[j] = *reinterpret_cast<const bf16x8*>(bp + j * 512);
      #pragma unroll
      for (int kt = 0; kt < 18; kt++) {
        const bf16x8 bcur = bq[kt % 6];
        if (kt < 12) bq[kt % 6] = *reinterpret_cast<const bf16x8*>(bp + (kt + 6) * 512);
        const bf16x8 af = *reinterpret_cast<const bf16x8*>(bufA + l5 * 296 + kt * 16 + hi * 8);
        acc1 = __builtin_amdgcn_mfma_f32_32x32x16_bf16(af, bcur, acc1, 0, 0, 0);
      }
    }
    __syncthreads();  // prev chunk's GEMM2 reads of bufB complete
    if (act) {
      const int colg = nt * 32 + l5;
      const float bias = (colg < 530) ? b1[colg] : 0.f;
      const int coll = nh * 32 + l5;
      #pragma unroll
      for (int r = 0; r < 16; r++) {
        const int rowi = (r & 3) + 8 * (r >> 2) + 4 * hi;
        bufB[rowi * 136 + coll] = f2b(silu_f(acc1[r] + bias));
      }
    }
    __syncthreads();  // Y1 chunk ready

    const int nk2 = (c < 4) ? 8 : 2;   // folds per unrolled c
    const u16* bp2 = W2s + ((((nh * 34 + c * 8) << 6) + lane) << 3);
    bf16x8 bq2[4];
    #pragma unroll
    for (int j = 0; j < 4; j++)
      if (j < nk2) bq2[j] = *reinterpret_cast<const bf16x8*>(bp2 + j * 512);
    #pragma unroll
    for (int k2 = 0; k2 < 8; k2++) {
      if (k2 < nk2) {
        const bf16x8 bcur = bq2[k2 % 4];
        if (k2 + 4 < nk2) bq2[k2 % 4] = *reinterpret_cast<const bf16x8*>(bp2 + (k2 + 4) * 512);
        const bf16x8 a = *reinterpret_cast<const bf16x8*>(bufB + l5 * 136 + k2 * 16 + hi * 8);
        acc2 = __builtin_amdgcn_mfma_f32_32x32x16_bf16(a, bcur, acc2, 0, 0, 0);
      }
    }
  }
  __syncthreads();  // all GEMM2 reads of bufB done

  // ef = silu(acc2 + b2): keep in regs, write bf16 to bufB [32][136]
  f32x16 efv;
  {
    const int col = nh * 32 + l5;
    const float bias = b2[col];
    #pragma unroll
    for (int r = 0; r < 16; r++) {
      const int rowi = (r & 3) + 8 * (r >> 2) + 4 * hi;
      efv[r] = silu_f(acc2[r] + bias);
      bufB[rowi * 136 + col] = f2b(efv[r]);
    }
  }
  __syncthreads();  // ef ready

  // GEMM3: ef[32,128] x WC1[128,256]; wave nh: n-tiles nh*2+{0,1}
  // flattened 16 B-loads (kt*2+i), rolling FIFO distance 4
  f32x16 acc3[2];
  #pragma unroll
  for (int i = 0; i < 2; i++)
    #pragma unroll
    for (int t = 0; t < 16; t++) acc3[i][t] = 0.f;
  {
    bf16x8 bq3[4];
    #pragma unroll
    for (int j = 0; j < 4; j++) {
      const int kt0 = j >> 1, i0 = j & 1;
      bq3[j] = *reinterpret_cast<const bf16x8*>(
          WC1s + (((((nh * 2 + i0) * 8 + kt0) << 6) + lane) << 3));
    }
    #pragma unroll
    for (int kt = 0; kt < 8; kt++) {
      const bf16x8 a = *reinterpret_cast<const bf16x8*>(bufB + l5 * 136 + kt * 16 + hi * 8);
      #pragma unroll
      for (int i = 0; i < 2; i++) {
        const int q = kt * 2 + i;
        const bf16x8 bcur = bq3[q % 4];
        if (q + 4 < 16) {
          const int qn = q + 4, ktn = qn >> 1, in = qn & 1;
          bq3[q % 4] = *reinterpret_cast<const bf16x8*>(
              WC1s + (((((nh * 2 + in) * 8 + ktn) << 6) + lane) << 3));
        }
        acc3[i] = __builtin_amdgcn_mfma_f32_32x32x16_bf16(a, bcur, acc3[i], 0, 0, 0);
      }
    }
  }

  // agg_h packed-bf16 atomics (drain hides under epi3)
  {
    const int col = nh * 32 + l5;
    #pragma unroll
    for (int r = 0; r < 16; r++) {
      const float other = __shfl_xor(efv[r], 1);
      if ((l5 & 1) == 0) {
        const int rowi = (r & 3) + 8 * (r >> 2) + 4 * hi;
        pk_atomic_bf16(agg_h + (size_t)row_s[rowi] * 128 + col, efv[r], other);
      }
    }
  }

  // epi3 -> bufA as Y3 [32][264]
  #pragma unroll
  for (int i = 0; i < 2; i++) {
    const int col = (nh * 2 + i) * 32 + l5;
    const float bias = bc1[col];
    #pragma unroll
    for (int r = 0; r < 16; r++) {
      const int rowi = (r & 3) + 8 * (r >> 2) + 4 * hi;
      bufA[rowi * 264 + col] = f2b(silu_f(acc3[i][r] + bias));
    }
  }
  __syncthreads();  // Y3 ready

  // GEMM4 (wave 0 only): Y3[32,256] x WC2[256,32(3)]; FIFO distance 4 over 16 k-steps
  if (nh == 0) {
    f32x16 acc4;
    #pragma unroll
    for (int t = 0; t < 16; t++) acc4[t] = 0.f;
    const u16* bp4 = WC2s + (lane << 3);
    bf16x8 bq4[4];
    #pragma unroll
    for (int j = 0; j < 4; j++) bq4[j] = *reinterpret_cast<const bf16x8*>(bp4 + j * 512);
    #pragma unroll
    for (int kt = 0; kt < 16; kt++) {
      const bf16x8 bcur = bq4[kt % 4];
      if (kt < 12) bq4[kt % 4] = *reinterpret_cast<const bf16x8*>(bp4 + (kt + 4) * 512);
      const bf16x8 a = *reinterpret_cast<const bf16x8*>(bufA + l5 * 264 + kt * 16 + hi * 8);
      acc4 = __builtin_amdgcn_mfma_f32_32x32x16_bf16(a, bcur, acc4, 0, 0, 0);
    }
    if (l5 < 3) {
      #pragma unroll
      for (int r = 0; r < 16; r++)
        phi_s[(r & 3) + 8 * (r >> 2) + 4 * hi][l5] = acc4[r];
    }
    if (lane < 32) {
      const int r = row_s[lane], ci = eidx[NE + e0 + lane];
      float cd[9];
      #pragma unroll
      for (int i = 0; i < 9; i++) cd[i] = coord[r * 9 + i] - coord[ci * 9 + i];
      const float p0 = phi_s[lane][0], p1 = phi_s[lane][1], p2 = phi_s[lane][2];
      #pragma unroll
      for (int d = 0; d < 3; d++) {
        atomicAdd(&agg_c[(size_t)r * 9 + 0 + d], cd[0 + d] * p0);
        atomicAdd(&agg_c[(size_t)r * 9 + 3 + d], cd[3 + d] * p1);
        atomicAdd(&agg_c[(size_t)r * 9 + 6 + d], cd[6 + d] * p2);
      }
      atomicAdd(&cnt[r], 1.f);
    }
  }
}

// ---------------- node MLP (16x16 path; agg_h bf16) ----------------
__global__ __launch_bounds__(512)
void node_kernel(const float* __restrict__ h, const u16* __restrict__ hb,
                 const u16* __restrict__ aggh,
                 const u16* __restrict__ WN1s, const float* __restrict__ nb1,
                 const u16* __restrict__ WN2s, const float* __restrict__ nb2,
                 float* __restrict__ out) {
  __shared__ __align__(16) u16 buf[64 * 520];
  const int tid = threadIdx.x;
  const int lane = tid & 63;
  const int w = tid >> 6;
  const int l_lo = lane & 15;
  const int l_hi = lane >> 4;
  const int n0 = blockIdx.x << 6;

  for (int q = tid; q < 2048; q += 512) {
    const int e = q >> 5, sub = q & 31, which = sub >> 4, j = sub & 15;
    const int row = n0 + e;
    const u16* src = which ? aggh : hb;
    int4 v;
    if (row < NN) v = *reinterpret_cast<const int4*>(src + (size_t)row * 128 + j * 8);
    else { v.x = v.y = v.z = v.w = 0; }
    *reinterpret_cast<int4*>(buf + e * 264 + which * 128 + j * 8) = v;
  }
  __syncthreads();

  f32x4 acc[4][4];
  #pragma unroll
  for (int i = 0; i < 4; i++)
    #pragma unroll
    for (int m = 0; m < 4; m++) acc[i][m] = {0.f, 0.f, 0.f, 0.f};
  for (int kt = 0; kt < 8; kt++) {
    bf16x8 af[4];
    #pragma unroll
    for (int m = 0; m < 4; m++)
      af[m] = *reinterpret_cast<const bf16x8*>(buf + (m * 16 + l_lo) * 264 + kt * 32 + l_hi * 8);
    #pragma unroll
    for (int i = 0; i < 4; i++) {
      const int nt = w + 8 * i;
      const bf16x8 bfr = *reinterpret_cast<const bf16x8*>(WN1s + (((nt * 8 + kt) << 6) + lane) * 8);
      #pragma unroll
      for (int m = 0; m < 4; m++)
        acc[i][m] = __builtin_amdgcn_mfma_f32_16x16x32_bf16(af[m], bfr, acc[i][m], 0, 0, 0);
    }
  }
  __syncthreads();
  #pragma unroll
  for (int i = 0; i < 4; i++) {
    const int nt = w + 8 * i;
    const int coln = nt * 16 + l_lo;
    const float bias = nb1[coln];
    #pragma unroll
    for (int m = 0; m < 4; m++)
      #pragma unroll
      for (int r = 0; r < 4; r++) {
        const int row = m * 16 + l_hi * 4 + r;
        buf[row * 520 + coln] = f2b(silu_f(acc[i][m][r] + bias));
      }
  }
  __syncthreads();

  f32x4 acc2[4];
  #pragma unroll
  for (int m = 0; m < 4; m++) acc2[m] = {0.f, 0.f, 0.f, 0.f};
  for (int kt = 0; kt < 16; kt++) {
    const bf16x8 bfr = *reinterpret_cast<const bf16x8*>(WN2s + (((w * 16 + kt) << 6) + lane) * 8);
    #pragma unroll
    for (int m = 0; m < 4; m++) {
      const bf16x8 af = *reinterpret_cast<const bf16x8*>(buf + (m * 16 + l_lo) * 520 + kt * 32 + l_hi * 8);
      acc2[m] = __builtin_amdgcn_mfma_f32_16x16x32_bf16(af, bfr, acc2[m], 0, 0, 0);
    }
  }
  {
    const int coln = w * 16 + l_lo;
    const float bias = nb2[coln];
    #pragma unroll
    for (int m = 0; m < 4; m++)
      #pragma unroll
      for (int r = 0; r < 4; r++) {
        const int row = n0 + m * 16 + l_hi * 4 + r;
        if (row < NN)
          out[(size_t)row * 128 + coln] = h[(size_t)row * 128 + coln] + silu_f(acc2[m][r] + bias);
      }
  }
}

__global__ void coord_kernel(const float* __restrict__ coord, const float* __restrict__ agg_c,
                             const float* __restrict__ cnt, float* __restrict__ out) {
  int i = blockIdx.x * 256 + threadIdx.x;
  if (i < NN * 9) {
    float c = fmaxf(cnt[i / 9], 1.f);
    float v = agg_c[i] / c;
    v = fminf(fmaxf(v, -10.f), 10.f);
    out[i] = coord[i] + v;
  }
}

extern "C" void kernel_launch(void* const* d_in, const int* in_sizes, int n_in,
                              void* d_out, int out_size, void* d_ws, size_t ws_size,
                              hipStream_t stream) {
  (void)in_sizes; (void)n_in; (void)out_size; (void)ws_size;
  const float* h     = (const float*)d_in[0];
  const int*   eidx  = (const int*)d_in[1];
  const float* coord = (const float*)d_in[2];
  const float* eW1 = (const float*)d_in[3];  const float* eb1 = (const float*)d_in[4];
  const float* eW2 = (const float*)d_in[5];  const float* eb2 = (const float*)d_in[6];
  const float* nW1 = (const float*)d_in[7];  const float* nb1 = (const float*)d_in[8];
  const float* nW2 = (const float*)d_in[9];  const float* nb2 = (const float*)d_in[10];
  const float* cW1 = (const float*)d_in[11]; const float* cb1 = (const float*)d_in[12];
  const float* cW2 = (const float*)d_in[13];

  char* ws = (char*)d_ws;
  u16* W1s  = (u16*)(ws + OFF_W1);
  u16* W2s  = (u16*)(ws + OFF_W2);
  u16* WC1s = (u16*)(ws + OFF_WC1);
  u16* WC2s = (u16*)(ws + OFF_WC2);
  u16* WN1s = (u16*)(ws + OFF_WN1);
  u16* WN2s = (u16*)(ws + OFF_WN2);
  u16* hb   = (u16*)(ws + OFF_HB);
  u16* agg_h  = (u16*)(ws + OFF_AGGH);
  float* agg_c = (float*)(ws + OFF_AGGC);
  float* cnt   = (float*)(ws + OFF_CNT);
  float* out   = (float*)d_out;

  hipMemsetAsync(ws + OFF_AGGH, 0, SZ_AGGH + SZ_AGGC + SZ_CNT, stream);

  swz32_kernel<<<18 * 17 * 2, 256, 0, stream>>>(eW1, W1s, 265, 530, 18, 17);
  swz32_kernel<<<34 * 4 * 2, 256, 0, stream>>>(eW2, W2s, 530, 128, 34, 4);
  swz32_kernel<<<8 * 8 * 2, 256, 0, stream>>>(cW1, WC1s, 128, 256, 8, 8);
  swz32_kernel<<<16 * 1 * 2, 256, 0, stream>>>(cW2, WC2s, 256, 3, 16, 1);
  swz_kernel<<<8 * 32 * 2, 256, 0, stream>>>(nW1, WN1s, 256, 512, 8, 32);
  swz_kernel<<<16 * 8 * 2, 256, 0, stream>>>(nW2, WN2s, 512, 128, 16, 8);
  tob16_kernel<<<(NN * 128 + 255) / 256, 256, 0, stream>>>(h, hb, NN * 128);

  edge_kernel<<<NE / 32, 256, 0, stream>>>(hb, eidx, coord, W1s, eb1, W2s, eb2,
                                           WC1s, cb1, WC2s, agg_h, agg_c, cnt);
  node_kernel<<<(NN + 63) / 64, 512, 0, stream>>>(h, hb, agg_h, WN1s, nb1, WN2s, nb2, out);
  coord_kernel<<<(NN * 9 + 255) / 256, 256, 0, stream>>>(coord, agg_c, cnt, out + (size_t)NN * 128);
}